// Round 5
// baseline (855.494 us; speedup 1.0000x reference)
//
#include <hip/hip_runtime.h>

// ---------------------------------------------------------------------------
// NucleusMoEImageTransformerBlock round 5.
// B=2 SI=1024 ST=512 D=2048 H=16 KV=4 HD=128 E=8 F=1024 TOPK=2
// Round-5: GEMM K-loop reverted to m97 2-barrier single-buffer schedule
// (stage -> sync -> compute -> sync), 32 KB LDS -> ~5 blocks/CU so the
// vmcnt(0) barrier drain overlaps across co-resident blocks. Keeps
// global_load_lds(16B) + XOR chunk swizzle (bank-conflict-free, verified r4).
// ---------------------------------------------------------------------------

typedef __attribute__((ext_vector_type(8))) __bf16 bf16x8;
typedef __attribute__((ext_vector_type(8))) unsigned short u16x8;
typedef __attribute__((ext_vector_type(4))) float f32x4;

__device__ __forceinline__ unsigned short f2bf(float x) {
  unsigned u = __builtin_bit_cast(unsigned, x);
  u += 0x7fffu + ((u >> 16) & 1u);        // RNE
  return (unsigned short)(u >> 16);
}
__device__ __forceinline__ float bf2f(unsigned short b) {
  return __builtin_bit_cast(float, ((unsigned)b) << 16);
}

__device__ __forceinline__ void glds16(const unsigned short* g, unsigned short* l) {
  __builtin_amdgcn_global_load_lds(
      (const __attribute__((address_space(1))) void*)g,
      (__attribute__((address_space(3))) void*)l, 16, 0, 0);
}

// ---------------------------------------------------------------------------
// Weight convert+transpose: W f32 [K][N] -> WT bf16 [N][K].
// ---------------------------------------------------------------------------
__global__ __launch_bounds__(256) void convert_w(
    const float* __restrict__ W, unsigned short* __restrict__ WT,
    int K, int N)
{
  __shared__ unsigned short T[64][66];
  const float* Wz = W + (size_t)blockIdx.z * K * N;
  unsigned short* WTz = WT + (size_t)blockIdx.z * K * N;
  const int k0 = blockIdx.x * 64, n0 = blockIdx.y * 64;
  const int tid = threadIdx.x;
  #pragma unroll
  for (int i = tid; i < 64 * 16; i += 256) {
    int k = i >> 4, n4 = (i & 15) * 4;
    float4 v = *(const float4*)&Wz[(size_t)(k0 + k) * N + n0 + n4];
    T[n4 + 0][k] = f2bf(v.x);
    T[n4 + 1][k] = f2bf(v.y);
    T[n4 + 2][k] = f2bf(v.z);
    T[n4 + 3][k] = f2bf(v.w);
  }
  __syncthreads();
  #pragma unroll
  for (int i = tid; i < 64 * 8; i += 256) {
    int n = i >> 3, k8 = (i & 7) * 8;
    *(u16x8*)&WTz[(size_t)(n0 + n) * K + k0 + k8] = *(const u16x8*)&T[n][k8];
  }
}

// ---------------------------------------------------------------------------
// Dense GEMM: C[M,N] = A[M,K] @ BT[N,K]^T (+resid). bf16 in, f32 out.
// 128x128 tile, BK=64, single-buffer m97 schedule, XOR chunk swizzle.
// ---------------------------------------------------------------------------
__global__ __launch_bounds__(256) void gemm_bb(
    const unsigned short* __restrict__ A, const unsigned short* __restrict__ BT,
    float* __restrict__ C, const float* __restrict__ resid,
    int M, int N, int K)
{
  __shared__ unsigned short As[128 * 64];
  __shared__ unsigned short Bs[128 * 64];
  const int tid = threadIdx.x, lane = tid & 63, wid = tid >> 6;
  const int bm = blockIdx.x * 128, bn = blockIdx.y * 128;
  const int wm = (wid >> 1) * 64, wn = (wid & 1) * 64;
  const int l16 = lane & 15, g4 = lane >> 4;
  const int rseg = lane >> 3;                    // 0..7 row within segment
  const int csw  = ((lane & 7) ^ rseg) * 8;      // swizzled src col (shorts)
  const unsigned short* aSrc[4];
  const unsigned short* bSrc[4];
  #pragma unroll
  for (int p = 0; p < 4; ++p) {
    int row = (p * 4 + wid) * 8 + rseg;
    aSrc[p] = A  + (size_t)(bm + row) * K + csw;
    bSrc[p] = BT + (size_t)(bn + row) * K + csw;
  }
  f32x4 acc[4][4] = {};
  const int NT = K >> 6;
  for (int t = 0; t < NT; ++t) {
    const int k0 = t << 6;
    #pragma unroll
    for (int p = 0; p < 4; ++p) glds16(aSrc[p] + k0, &As[(p * 4 + wid) * 512]);
    #pragma unroll
    for (int p = 0; p < 4; ++p) glds16(bSrc[p] + k0, &Bs[(p * 4 + wid) * 512]);
    __syncthreads();
    #pragma unroll
    for (int ks = 0; ks < 2; ++ks) {
      bf16x8 af[4], bf[4];
      #pragma unroll
      for (int i = 0; i < 4; ++i) {
        int ra = wm + i * 16 + l16;
        int rb = wn + i * 16 + l16;
        int ch = ((ks * 4 + g4) ^ (l16 & 7)) * 8;
        af[i] = *(const bf16x8*)&As[ra * 64 + ch];
        bf[i] = *(const bf16x8*)&Bs[rb * 64 + ch];
      }
      #pragma unroll
      for (int mi = 0; mi < 4; ++mi)
        #pragma unroll
        for (int ni = 0; ni < 4; ++ni)
          acc[mi][ni] = __builtin_amdgcn_mfma_f32_16x16x32_bf16(af[mi], bf[ni], acc[mi][ni], 0, 0, 0);
    }
    __syncthreads();
  }
  const int r4 = g4 * 4;
  #pragma unroll
  for (int mi = 0; mi < 4; ++mi)
    #pragma unroll
    for (int ni = 0; ni < 4; ++ni)
      #pragma unroll
      for (int r = 0; r < 4; ++r) {
        int row = bm + wm + mi * 16 + r4 + r;
        int col = bn + wn + ni * 16 + l16;
        float v = acc[mi][ni][r];
        if (resid) v += resid[(size_t)row * N + col];
        C[(size_t)row * N + col] = v;
      }
}

// ---------------------------------------------------------------------------
// Expert-batched MoE GEMM, same schedule, optional row gather; invalid rows
// stage from a zero page.
// ---------------------------------------------------------------------------
__global__ __launch_bounds__(256) void gemm_moe_bb(
    const unsigned short* __restrict__ A, const unsigned short* __restrict__ BTall,
    float* __restrict__ C,
    const int* __restrict__ counts, const int* __restrict__ offsets,
    const int* __restrict__ pair_token, const unsigned short* __restrict__ zbuf,
    int gather, int K, int N)
{
  const int e = blockIdx.z;
  const int cnt = counts[e];
  const int bm = blockIdx.x * 128;
  if (bm >= cnt) return;
  const int base = offsets[e];
  const int bn = blockIdx.y * 128;
  __shared__ unsigned short As[128 * 64];
  __shared__ unsigned short Bs[128 * 64];
  const int tid = threadIdx.x, lane = tid & 63, wid = tid >> 6;
  const int wm = (wid >> 1) * 64, wn = (wid & 1) * 64;
  const int l16 = lane & 15, g4 = lane >> 4;
  const int rseg = lane >> 3;
  const int csw  = ((lane & 7) ^ rseg) * 8;
  const unsigned short* BT = BTall + (size_t)e * N * K;
  const unsigned short* aSrc[4];
  const unsigned short* bSrc[4];
  int aOk[4];
  #pragma unroll
  for (int p = 0; p < 4; ++p) {
    int row = (p * 4 + wid) * 8 + rseg;
    int lr = bm + row;
    int tok = -1;
    if (lr < cnt) tok = gather ? pair_token[base + lr] : base + lr;
    aOk[p] = (tok >= 0);
    aSrc[p] = aOk[p] ? (A + (size_t)tok * K + csw) : (zbuf + csw);
    bSrc[p] = BT + (size_t)(bn + row) * K + csw;
  }
  f32x4 acc[4][4] = {};
  const int NT = K >> 6;
  for (int t = 0; t < NT; ++t) {
    const int k0 = t << 6;
    #pragma unroll
    for (int p = 0; p < 4; ++p)
      glds16(aSrc[p] + (aOk[p] ? k0 : 0), &As[(p * 4 + wid) * 512]);
    #pragma unroll
    for (int p = 0; p < 4; ++p)
      glds16(bSrc[p] + k0, &Bs[(p * 4 + wid) * 512]);
    __syncthreads();
    #pragma unroll
    for (int ks = 0; ks < 2; ++ks) {
      bf16x8 af[4], bf[4];
      #pragma unroll
      for (int i = 0; i < 4; ++i) {
        int ra = wm + i * 16 + l16;
        int rb = wn + i * 16 + l16;
        int ch = ((ks * 4 + g4) ^ (l16 & 7)) * 8;
        af[i] = *(const bf16x8*)&As[ra * 64 + ch];
        bf[i] = *(const bf16x8*)&Bs[rb * 64 + ch];
      }
      #pragma unroll
      for (int mi = 0; mi < 4; ++mi)
        #pragma unroll
        for (int ni = 0; ni < 4; ++ni)
          acc[mi][ni] = __builtin_amdgcn_mfma_f32_16x16x32_bf16(af[mi], bf[ni], acc[mi][ni], 0, 0, 0);
    }
    __syncthreads();
  }
  const int r4 = g4 * 4;
  #pragma unroll
  for (int mi = 0; mi < 4; ++mi)
    #pragma unroll
    for (int ni = 0; ni < 4; ++ni)
      #pragma unroll
      for (int r = 0; r < 4; ++r) {
        int lrow = bm + wm + mi * 16 + r4 + r;
        int col  = bn + wn + ni * 16 + l16;
        if (lrow < cnt)
          C[(size_t)(base + lrow) * N + col] = acc[mi][ni][r];
      }
}

// ---------------------------------------------------------------------------
// RMSNorm over D=2048, f32 in -> bf16 out (+ optional exact f32 out).
// ---------------------------------------------------------------------------
__global__ __launch_bounds__(256) void rmsnorm_rows(
    const float* __restrict__ in, const float* __restrict__ w,
    unsigned short* __restrict__ out, float* __restrict__ out32)
{
  const int row = blockIdx.x;
  const int tid = threadIdx.x;
  const float* x = in + (size_t)row * 2048;
  float4 a = *(const float4*)&x[tid * 8];
  float4 b = *(const float4*)&x[tid * 8 + 4];
  float s = a.x*a.x + a.y*a.y + a.z*a.z + a.w*a.w
          + b.x*b.x + b.y*b.y + b.z*b.z + b.w*b.w;
  #pragma unroll
  for (int off = 1; off < 64; off <<= 1) s += __shfl_xor(s, off);
  __shared__ float red[4];
  if ((tid & 63) == 0) red[tid >> 6] = s;
  __syncthreads();
  float inv = rsqrtf((red[0] + red[1] + red[2] + red[3]) * (1.f / 2048.f) + 1e-6f);
  float4 wa = *(const float4*)&w[tid * 8];
  float4 wb = *(const float4*)&w[tid * 8 + 4];
  float y[8] = {a.x * inv * wa.x, a.y * inv * wa.y, a.z * inv * wa.z, a.w * inv * wa.w,
                b.x * inv * wb.x, b.y * inv * wb.y, b.z * inv * wb.z, b.w * inv * wb.w};
  unsigned short* o = out + (size_t)row * 2048 + tid * 8;
  #pragma unroll
  for (int j = 0; j < 8; ++j) o[j] = f2bf(y[j]);
  if (out32) {
    float* o32 = out32 + (size_t)row * 2048 + tid * 8;
    *(float4*)&o32[0] = make_float4(y[0], y[1], y[2], y[3]);
    *(float4*)&o32[4] = make_float4(y[4], y[5], y[6], y[7]);
  }
}

__global__ __launch_bounds__(256) void f32_to_bf16_k(
    const float* __restrict__ in, unsigned short* __restrict__ out, int n)
{
  int i = (blockIdx.x * 256 + threadIdx.x) * 4;
  if (i + 3 < n) {
    float4 v = *(const float4*)&in[i];
    out[i + 0] = f2bf(v.x); out[i + 1] = f2bf(v.y);
    out[i + 2] = f2bf(v.z); out[i + 3] = f2bf(v.w);
  }
}

// ---------------------------------------------------------------------------
// Per-(b,s,h) head RMSNorm + RoPE, relayout to (B, NH, seq_total, 128) bf16.
// ---------------------------------------------------------------------------
__global__ __launch_bounds__(256) void qk_norm_rope(
    const float* __restrict__ raw, int ld, const float* __restrict__ nw,
    const float* __restrict__ cosT, const float* __restrict__ sinT,
    unsigned short* __restrict__ out,
    int S, int NH, int seq_total, int s_off, float premul)
{
  int rowid = blockIdx.x * 4 + (threadIdx.x >> 6);
  int lane  = threadIdx.x & 63;
  int b = rowid / (S * NH);
  int rem = rowid % (S * NH);
  int s = rem / NH, h = rem % NH;
  const float* src = raw + (size_t)(b * S + s) * ld + h * 128;
  float2 xv = *(const float2*)&src[lane * 2];
  float ss = xv.x * xv.x + xv.y * xv.y;
  #pragma unroll
  for (int off = 1; off < 64; off <<= 1) ss += __shfl_xor(ss, off);
  float inv = rsqrtf(ss * (1.f / 128.f) + 1e-6f);
  float yr = xv.x * inv * nw[lane * 2];
  float yi = xv.y * inv * nw[lane * 2 + 1];
  float c  = cosT[s * 64 + lane], sn = sinT[s * 64 + lane];
  float orr = (yr * c - yi * sn) * premul;
  float oi  = (yr * sn + yi * c) * premul;
  unsigned short* dst = out + ((size_t)(b * NH + h) * seq_total + (s + s_off)) * 128;
  dst[lane * 2]     = f2bf(orr);
  dst[lane * 2 + 1] = f2bf(oi);
}

__global__ __launch_bounds__(256) void v_relayout(
    const float* __restrict__ raw, int ld, unsigned short* __restrict__ out,
    int S, int NH, int seq_total, int s_off)
{
  int rowid = blockIdx.x * 4 + (threadIdx.x >> 6);
  int lane  = threadIdx.x & 63;
  int b = rowid / (S * NH);
  int rem = rowid % (S * NH);
  int s = rem / NH, h = rem % NH;
  const float* src = raw + (size_t)(b * S + s) * ld + h * 128;
  float2 xv = *(const float2*)&src[lane * 2];
  unsigned short* dst = out + ((size_t)(b * NH + h) * seq_total + (s + s_off)) * 128;
  dst[lane * 2]     = f2bf(xv.x);
  dst[lane * 2 + 1] = f2bf(xv.y);
}

// ---------------------------------------------------------------------------
// Flash attention: 64 q-rows per block (4 waves x 16 rows), Sk tiles of 64.
// ---------------------------------------------------------------------------
__global__ __launch_bounds__(256) void attn_kernel(
    const unsigned short* __restrict__ q,    // (B,16,1024,128)
    const unsigned short* __restrict__ kbuf, // (B,4,1536,128)
    const unsigned short* __restrict__ vbuf, // (B,4,1536,128)
    unsigned short* __restrict__ o)          // (B*1024, 2048)
{
  const int SK = 1536;
  const int bh = blockIdx.y;
  const int b = bh >> 4, h = bh & 15, kvh = h >> 2;
  const int q0 = blockIdx.x * 64;
  const int tid = threadIdx.x, lane = tid & 63, wid = tid >> 6;
  const int l16 = lane & 15, kb = (lane >> 4) * 8, r4 = (lane >> 4) * 4;
  __shared__ unsigned short Ks[64][136];
  __shared__ unsigned short VT[128][72];
  __shared__ unsigned short Ps[4][16][72];
  const unsigned short* qrow =
      q + ((size_t)(b * 16 + h) * 1024 + q0 + wid * 16 + l16) * 128;
  bf16x8 qf[4];
  #pragma unroll
  for (int ks = 0; ks < 4; ++ks) qf[ks] = *(const bf16x8*)&qrow[ks * 32 + kb];
  float mrow[4] = {-1e30f, -1e30f, -1e30f, -1e30f};
  float lrow[4] = {0.f, 0.f, 0.f, 0.f};
  f32x4 oacc[8] = {};
  const unsigned short* kb_base = kbuf + (size_t)(b * 4 + kvh) * SK * 128;
  const unsigned short* vb_base = vbuf + (size_t)(b * 4 + kvh) * SK * 128;
  for (int kt = 0; kt < SK; kt += 64) {
    __syncthreads();
    #pragma unroll
    for (int c = tid; c < 1024; c += 256) {
      int r = c >> 4, cc = (c & 15) * 8;
      *(u16x8*)&Ks[r][cc] = *(const u16x8*)&kb_base[(size_t)(kt + r) * 128 + cc];
    }
    #pragma unroll
    for (int c = tid; c < 1024; c += 256) {
      int r = c >> 4, cc = (c & 15) * 8;
      u16x8 v = *(const u16x8*)&vb_base[(size_t)(kt + r) * 128 + cc];
      #pragma unroll
      for (int j = 0; j < 8; ++j) VT[cc + j][r] = v[j];
    }
    __syncthreads();
    f32x4 sacc[4] = {};
    #pragma unroll
    for (int ks = 0; ks < 4; ++ks) {
      #pragma unroll
      for (int ni = 0; ni < 4; ++ni) {
        bf16x8 kf = *(const bf16x8*)&Ks[ni * 16 + l16][ks * 32 + kb];
        sacc[ni] = __builtin_amdgcn_mfma_f32_16x16x32_bf16(qf[ks], kf, sacc[ni], 0, 0, 0);
      }
    }
    float pv[4][4], alpha[4];
    #pragma unroll
    for (int r = 0; r < 4; ++r) {
      float tm = fmaxf(fmaxf(sacc[0][r], sacc[1][r]), fmaxf(sacc[2][r], sacc[3][r]));
      #pragma unroll
      for (int off = 1; off < 16; off <<= 1) tm = fmaxf(tm, __shfl_xor(tm, off));
      float mn = fmaxf(mrow[r], tm);
      alpha[r] = __expf(mrow[r] - mn);
      float s = 0.f;
      #pragma unroll
      for (int ni = 0; ni < 4; ++ni) {
        float p = __expf(sacc[ni][r] - mn);
        pv[ni][r] = p; s += p;
      }
      #pragma unroll
      for (int off = 1; off < 16; off <<= 1) s += __shfl_xor(s, off);
      lrow[r] = lrow[r] * alpha[r] + s;
      mrow[r] = mn;
    }
    #pragma unroll
    for (int ni = 0; ni < 8; ++ni)
      #pragma unroll
      for (int r = 0; r < 4; ++r) oacc[ni][r] *= alpha[r];
    #pragma unroll
    for (int ni = 0; ni < 4; ++ni)
      #pragma unroll
      for (int r = 0; r < 4; ++r)
        Ps[wid][r4 + r][ni * 16 + l16] = f2bf(pv[ni][r]);
    asm volatile("s_waitcnt lgkmcnt(0)" ::: "memory");
    __builtin_amdgcn_sched_barrier(0);
    #pragma unroll
    for (int ks = 0; ks < 2; ++ks) {
      bf16x8 pf = *(const bf16x8*)&Ps[wid][l16][ks * 32 + kb];
      #pragma unroll
      for (int ni = 0; ni < 8; ++ni) {
        bf16x8 vf = *(const bf16x8*)&VT[ni * 16 + l16][ks * 32 + kb];
        oacc[ni] = __builtin_amdgcn_mfma_f32_16x16x32_bf16(pf, vf, oacc[ni], 0, 0, 0);
      }
    }
  }
  #pragma unroll
  for (int ni = 0; ni < 8; ++ni)
    #pragma unroll
    for (int r = 0; r < 4; ++r) {
      float val = oacc[ni][r] / lrow[r];
      size_t row = (size_t)b * 1024 + q0 + wid * 16 + r4 + r;
      o[row * 2048 + h * 128 + ni * 16 + l16] = f2bf(val);
    }
}

// ---------------------------------------------------------------------------
// Router: one wave per token, f32 input (exact), f32 accumulate.
// ---------------------------------------------------------------------------
__global__ __launch_bounds__(64) void router_kernel(
    const float* __restrict__ xt32, const float* __restrict__ rw,
    int* __restrict__ topi, float* __restrict__ topw, int* __restrict__ counts)
{
  int t = blockIdx.x, lane = threadIdx.x;
  float acc[8] = {};
  const float* x = xt32 + (size_t)t * 2048;
  for (int d0 = lane * 4; d0 < 2048; d0 += 256) {
    float4 xv = *(const float4*)&x[d0];
    float xa[4] = {xv.x, xv.y, xv.z, xv.w};
    #pragma unroll
    for (int j = 0; j < 4; ++j) {
      const float4 r0 = *(const float4*)&rw[(d0 + j) * 8];
      const float4 r1 = *(const float4*)&rw[(d0 + j) * 8 + 4];
      acc[0] += xa[j] * r0.x; acc[1] += xa[j] * r0.y;
      acc[2] += xa[j] * r0.z; acc[3] += xa[j] * r0.w;
      acc[4] += xa[j] * r1.x; acc[5] += xa[j] * r1.y;
      acc[6] += xa[j] * r1.z; acc[7] += xa[j] * r1.w;
    }
  }
  #pragma unroll
  for (int e = 0; e < 8; ++e)
    #pragma unroll
    for (int off = 1; off < 64; off <<= 1) acc[e] += __shfl_xor(acc[e], off);
  if (lane == 0) {
    float v0 = acc[0]; int e0 = 0;
    #pragma unroll
    for (int e = 1; e < 8; ++e) if (acc[e] > v0) { v0 = acc[e]; e0 = e; }
    float v1 = -1e30f; int e1 = 0;
    #pragma unroll
    for (int e = 0; e < 8; ++e) if (e != e0 && acc[e] > v1) { v1 = acc[e]; e1 = e; }
    float x1 = expf(v1 - v0);
    float w0 = 1.f / (1.f + x1);
    float w1 = x1 / (1.f + x1);
    topi[2 * t] = e0; topi[2 * t + 1] = e1;
    topw[2 * t] = w0; topw[2 * t + 1] = w1;
    atomicAdd(&counts[e0], 1);
    atomicAdd(&counts[e1], 1);
  }
}

__global__ void scan_offsets(const int* __restrict__ counts, int* __restrict__ offsets)
{
  if (threadIdx.x == 0 && blockIdx.x == 0) {
    int a = 0;
    for (int e = 0; e < 8; ++e) { offsets[e] = a; a += counts[e]; }
    offsets[8] = a;
  }
}

__global__ __launch_bounds__(256) void scatter_pairs(
    const int* __restrict__ topi, const int* __restrict__ offsets,
    int* __restrict__ fill, int* __restrict__ pair_token, int* __restrict__ token_slot)
{
  int t = blockIdx.x * 256 + threadIdx.x;
  if (t >= 2048) return;
  #pragma unroll
  for (int k = 0; k < 2; ++k) {
    int e = topi[2 * t + k];
    int slot = offsets[e] + atomicAdd(&fill[e], 1);
    pair_token[slot] = t;
    token_slot[2 * t + k] = slot;
  }
}

__global__ __launch_bounds__(256) void act_silu(
    const float* __restrict__ gu, unsigned short* __restrict__ act)
{
  int p = blockIdx.x;
  int c = threadIdx.x * 4;
  float4 g = *(const float4*)&gu[(size_t)p * 2048 + c];
  float4 u = *(const float4*)&gu[(size_t)p * 2048 + 1024 + c];
  float gg[4] = {g.x, g.y, g.z, g.w};
  float uu[4] = {u.x, u.y, u.z, u.w};
  #pragma unroll
  for (int j = 0; j < 4; ++j) {
    float a = gg[j] / (1.f + __expf(-gg[j])) * uu[j];
    act[(size_t)p * 1024 + c + j] = f2bf(a);
  }
}

__global__ __launch_bounds__(256) void moe_combine(
    float* __restrict__ out, const float* __restrict__ eo,
    const int* __restrict__ token_slot, const float* __restrict__ topw)
{
  int t = blockIdx.x;
  int c = threadIdx.x * 8;
  int s0 = token_slot[2 * t], s1 = token_slot[2 * t + 1];
  float w0 = topw[2 * t], w1 = topw[2 * t + 1];
  #pragma unroll
  for (int j0 = 0; j0 < 8; j0 += 4) {
    float4 a = *(const float4*)&eo[(size_t)s0 * 2048 + c + j0];
    float4 b = *(const float4*)&eo[(size_t)s1 * 2048 + c + j0];
    float4 v = *(const float4*)&out[(size_t)t * 2048 + c + j0];
    v.x += w0 * a.x + w1 * b.x;
    v.y += w0 * a.y + w1 * b.y;
    v.z += w0 * a.z + w1 * b.z;
    v.w += w0 * a.w + w1 * b.w;
    *(float4*)&out[(size_t)t * 2048 + c + j0] = v;
  }
}

// ---------------------------------------------------------------------------
extern "C" void kernel_launch(void* const* d_in, const int* in_sizes, int n_in,
                              void* d_out, int out_size, void* d_ws, size_t ws_size,
                              hipStream_t stream)
{
  const float* hidden  = (const float*)d_in[0];
  const float* enc     = (const float*)d_in[1];
  const float* img_cos = (const float*)d_in[2];
  const float* img_sin = (const float*)d_in[3];
  const float* txt_cos = (const float*)d_in[4];
  const float* txt_sin = (const float*)d_in[5];
  const float* norm1_w = (const float*)d_in[6];
  const float* norm2_w = (const float*)d_in[7];
  const float* wq      = (const float*)d_in[8];
  const float* wk      = (const float*)d_in[9];
  const float* wv      = (const float*)d_in[10];
  const float* wk_txt  = (const float*)d_in[11];
  const float* wv_txt  = (const float*)d_in[12];
  const float* wo      = (const float*)d_in[13];
  const float* q_norm_w       = (const float*)d_in[14];
  const float* k_norm_w       = (const float*)d_in[15];
  const float* added_k_norm_w = (const float*)d_in[16];
  const float* router_w       = (const float*)d_in[17];
  const float* gate_up_proj   = (const float*)d_in[18];
  const float* down_proj      = (const float*)d_in[19];
  float* out = (float*)d_out;

  char* ws = (char*)d_ws;
  size_t off = 0;
  auto alloc = [&](size_t bytes) {
    void* p = ws + off;
    off += (bytes + 255) & ~(size_t)255;
    return p;
  };
  // --- bf16 transposed weights ---
  unsigned short* wqkvT  = (unsigned short*)alloc(3072ULL * 2048 * 2); // q|k|v rows
  unsigned short* wkvtT  = (unsigned short*)alloc(1024ULL * 2048 * 2); // k_txt|v_txt
  unsigned short* woT    = (unsigned short*)alloc(2048ULL * 2048 * 2);
  unsigned short* gupT   = (unsigned short*)alloc(8ULL * 2048 * 2048 * 2);
  unsigned short* dnT    = (unsigned short*)alloc(8ULL * 2048 * 1024 * 2);
  // --- activations ---
  unsigned short* x_bf   = (unsigned short*)alloc(2048ULL * 2048 * 2);
  unsigned short* enc_bf = (unsigned short*)alloc(1024ULL * 2048 * 2);
  float* qkvC = (float*)alloc(4096ULL * 2048 * 4); // [2048][3072] early; gu [4096][2048] late
  float* gu   = qkvC;                              // alias (disjoint lifetimes)
  float* kvtC = (float*)alloc(1024ULL * 1024 * 4); // [1024][1024] k_txt|v_txt
  unsigned short* qb   = (unsigned short*)alloc(2048ULL * 2048 * 2);
  unsigned short* kbuf = (unsigned short*)alloc(2ULL * 4 * 1536 * 128 * 2);
  unsigned short* vbuf = (unsigned short*)alloc(2ULL * 4 * 1536 * 128 * 2);
  unsigned short* obuf = (unsigned short*)alloc(2048ULL * 2048 * 2);
  unsigned short* act  = obuf;                     // alias (obuf dead after wo GEMM)
  unsigned short* xt   = (unsigned short*)alloc(2048ULL * 2048 * 2);
  float* xt32 = (float*)alloc(2048ULL * 2048 * 4);
  int*   ctrl  = (int*)alloc(64 * sizeof(int));    // counts[8] fill[8] offsets[9]
  int*   topi  = (int*)alloc(4096 * 4);
  float* topw  = (float*)alloc(4096 * 4);
  int*   tslot = (int*)alloc(4096 * 4);
  int*   ptok  = (int*)alloc(4096 * 4);
  unsigned short* zbuf = (unsigned short*)alloc(256);
  int* counts = ctrl, * fill = ctrl + 8, * offsets = ctrl + 16;

  hipMemsetAsync(ctrl, 0, 64, stream);
  hipMemsetAsync(zbuf, 0, 256, stream);

  const float scale = 0.08838834764831845f;  // 1/sqrt(128)

  // --- weight preprocessing: f32 [K][N] -> bf16 [N][K] ---
  convert_w<<<dim3(32, 32, 1), 256, 0, stream>>>(wq,     wqkvT,                    2048, 2048);
  convert_w<<<dim3(32,  8, 1), 256, 0, stream>>>(wk,     wqkvT + 2048ULL * 2048,   2048, 512);
  convert_w<<<dim3(32,  8, 1), 256, 0, stream>>>(wv,     wqkvT + 2560ULL * 2048,   2048, 512);
  convert_w<<<dim3(32,  8, 1), 256, 0, stream>>>(wk_txt, wkvtT,                    2048, 512);
  convert_w<<<dim3(32,  8, 1), 256, 0, stream>>>(wv_txt, wkvtT + 512ULL * 2048,    2048, 512);
  convert_w<<<dim3(32, 32, 1), 256, 0, stream>>>(wo,     woT,                      2048, 2048);
  convert_w<<<dim3(32, 32, 8), 256, 0, stream>>>(gate_up_proj, gupT,               2048, 2048);
  convert_w<<<dim3(16, 32, 8), 256, 0, stream>>>(down_proj,    dnT,                1024, 2048);

  rmsnorm_rows<<<2048, 256, 0, stream>>>(hidden, norm1_w, x_bf, nullptr);
  f32_to_bf16_k<<<2048, 256, 0, stream>>>(enc, enc_bf, 1024 * 2048);

  // fused qkv projection: [2048][2048] @ [3072][2048]^T -> [2048][3072]
  gemm_bb<<<dim3(16, 24), 256, 0, stream>>>(x_bf, wqkvT, qkvC, nullptr, 2048, 3072, 2048);
  // fused k/v txt projection: [1024][2048] @ [1024][2048]^T -> [1024][1024]
  gemm_bb<<<dim3(8, 8), 256, 0, stream>>>(enc_bf, wkvtT, kvtC, nullptr, 1024, 1024, 2048);

  qk_norm_rope<<<8192, 256, 0, stream>>>(qkvC, 3072, q_norm_w, img_cos, img_sin, qb,
                                         1024, 16, 1024, 0, scale);
  qk_norm_rope<<<2048, 256, 0, stream>>>(qkvC + 2048, 3072, k_norm_w, img_cos, img_sin, kbuf,
                                         1024, 4, 1536, 0, 1.0f);
  qk_norm_rope<<<1024, 256, 0, stream>>>(kvtC, 1024, added_k_norm_w, txt_cos, txt_sin, kbuf,
                                         512, 4, 1536, 1024, 1.0f);
  v_relayout<<<2048, 256, 0, stream>>>(qkvC + 2560, 3072, vbuf, 1024, 4, 1536, 0);
  v_relayout<<<1024, 256, 0, stream>>>(kvtC + 512, 1024, vbuf, 512, 4, 1536, 1024);

  attn_kernel<<<dim3(16, 32), 256, 0, stream>>>(qb, kbuf, vbuf, obuf);

  gemm_bb<<<dim3(16, 16), 256, 0, stream>>>(obuf, woT, out, hidden, 2048, 2048, 2048);

  rmsnorm_rows<<<2048, 256, 0, stream>>>(out, norm2_w, xt, xt32);
  router_kernel<<<2048, 64, 0, stream>>>(xt32, router_w, topi, topw, counts);
  scan_offsets<<<1, 64, 0, stream>>>(counts, offsets);
  scatter_pairs<<<8, 256, 0, stream>>>(topi, offsets, fill, ptok, tslot);

  gemm_moe_bb<<<dim3(16, 16, 8), 256, 0, stream>>>(xt, gupT, gu,
                                                   counts, offsets, ptok, zbuf, 1, 2048, 2048);
  act_silu<<<4096, 256, 0, stream>>>(gu, act);
  gemm_moe_bb<<<dim3(16, 16, 8), 256, 0, stream>>>(act, dnT, gu,
                                                   counts, offsets, ptok, zbuf, 0, 1024, 2048);
  moe_combine<<<2048, 256, 0, stream>>>(out, gu, tslot, topw);
}

// Round 6
// 820.464 us; speedup vs baseline: 1.0427x; 1.0427x over previous
//
#include <hip/hip_runtime.h>

// ---------------------------------------------------------------------------
// NucleusMoEImageTransformerBlock round 6.
// B=2 SI=1024 ST=512 D=2048 H=16 KV=4 HD=128 E=8 F=1024 TOPK=2
// Round-6: GEMM K-loop = double-buffered counted-vmcnt pipeline (T3+T4):
// issue next tile's global_load_lds, wait OWN vmcnt(8) (next tile stays in
// flight), raw s_barrier (no vmcnt(0) drain), compute, barrier. Latency
// hides in-block since the MoE grid gives only ~2 blocks/CU.
// ---------------------------------------------------------------------------

typedef __attribute__((ext_vector_type(8))) __bf16 bf16x8;
typedef __attribute__((ext_vector_type(8))) unsigned short u16x8;
typedef __attribute__((ext_vector_type(4))) float f32x4;

__device__ __forceinline__ unsigned short f2bf(float x) {
  unsigned u = __builtin_bit_cast(unsigned, x);
  u += 0x7fffu + ((u >> 16) & 1u);        // RNE
  return (unsigned short)(u >> 16);
}
__device__ __forceinline__ float bf2f(unsigned short b) {
  return __builtin_bit_cast(float, ((unsigned)b) << 16);
}

__device__ __forceinline__ void glds16(const unsigned short* g, unsigned short* l) {
  __builtin_amdgcn_global_load_lds(
      (const __attribute__((address_space(1))) void*)g,
      (__attribute__((address_space(3))) void*)l, 16, 0, 0);
}

// ---------------------------------------------------------------------------
// Weight convert+transpose: W f32 [K][N] -> WT bf16 [N][K].
// ---------------------------------------------------------------------------
__global__ __launch_bounds__(256) void convert_w(
    const float* __restrict__ W, unsigned short* __restrict__ WT,
    int K, int N)
{
  __shared__ unsigned short T[64][66];
  const float* Wz = W + (size_t)blockIdx.z * K * N;
  unsigned short* WTz = WT + (size_t)blockIdx.z * K * N;
  const int k0 = blockIdx.x * 64, n0 = blockIdx.y * 64;
  const int tid = threadIdx.x;
  #pragma unroll
  for (int i = tid; i < 64 * 16; i += 256) {
    int k = i >> 4, n4 = (i & 15) * 4;
    float4 v = *(const float4*)&Wz[(size_t)(k0 + k) * N + n0 + n4];
    T[n4 + 0][k] = f2bf(v.x);
    T[n4 + 1][k] = f2bf(v.y);
    T[n4 + 2][k] = f2bf(v.z);
    T[n4 + 3][k] = f2bf(v.w);
  }
  __syncthreads();
  #pragma unroll
  for (int i = tid; i < 64 * 8; i += 256) {
    int n = i >> 3, k8 = (i & 7) * 8;
    *(u16x8*)&WTz[(size_t)(n0 + n) * K + k0 + k8] = *(const u16x8*)&T[n][k8];
  }
}

// ---------------------------------------------------------------------------
// Dense GEMM: C[M,N] = A[M,K] @ BT[N,K]^T (+resid). bf16 in, f32 out.
// 128x128 tile, BK=64, counted-vmcnt dbuf pipeline, XOR chunk swizzle.
// ---------------------------------------------------------------------------
__global__ __launch_bounds__(256) void gemm_bb(
    const unsigned short* __restrict__ A, const unsigned short* __restrict__ BT,
    float* __restrict__ C, const float* __restrict__ resid,
    int M, int N, int K)
{
  __shared__ unsigned short As[2][128 * 64];
  __shared__ unsigned short Bs[2][128 * 64];
  const int tid = threadIdx.x, lane = tid & 63, wid = tid >> 6;
  const int bm = blockIdx.x * 128, bn = blockIdx.y * 128;
  const int wm = (wid >> 1) * 64, wn = (wid & 1) * 64;
  const int l16 = lane & 15, g4 = lane >> 4;
  const int rseg = lane >> 3;                    // 0..7 row within segment
  const int csw  = ((lane & 7) ^ rseg) * 8;      // swizzled src col (shorts)
  const unsigned short* aSrc[4];
  const unsigned short* bSrc[4];
  #pragma unroll
  for (int p = 0; p < 4; ++p) {
    int row = (p * 4 + wid) * 8 + rseg;
    aSrc[p] = A  + (size_t)(bm + row) * K + csw;
    bSrc[p] = BT + (size_t)(bn + row) * K + csw;
  }
  f32x4 acc[4][4] = {};
  const int NT = K >> 6;
  // prologue: stage tile 0 -> buf 0
  #pragma unroll
  for (int p = 0; p < 4; ++p) glds16(aSrc[p], &As[0][(p * 4 + wid) * 512]);
  #pragma unroll
  for (int p = 0; p < 4; ++p) glds16(bSrc[p], &Bs[0][(p * 4 + wid) * 512]);
  for (int t = 0; t < NT; ++t) {
    const int cur = t & 1;
    if (t + 1 < NT) {
      const int k0 = (t + 1) << 6;
      #pragma unroll
      for (int p = 0; p < 4; ++p) glds16(aSrc[p] + k0, &As[cur ^ 1][(p * 4 + wid) * 512]);
      #pragma unroll
      for (int p = 0; p < 4; ++p) glds16(bSrc[p] + k0, &Bs[cur ^ 1][(p * 4 + wid) * 512]);
      asm volatile("s_waitcnt vmcnt(8)" ::: "memory");  // own tile-t done; t+1 in flight
    } else {
      asm volatile("s_waitcnt vmcnt(0)" ::: "memory");
    }
    __builtin_amdgcn_s_barrier();                        // everyone's tile-t landed
    __builtin_amdgcn_sched_barrier(0);
    const unsigned short* ab = &As[cur][0];
    const unsigned short* bb = &Bs[cur][0];
    #pragma unroll
    for (int ks = 0; ks < 2; ++ks) {
      bf16x8 af[4], bf[4];
      #pragma unroll
      for (int i = 0; i < 4; ++i) {
        int ra = wm + i * 16 + l16;
        int rb = wn + i * 16 + l16;
        int ch = ((ks * 4 + g4) ^ (l16 & 7)) * 8;
        af[i] = *(const bf16x8*)&ab[ra * 64 + ch];
        bf[i] = *(const bf16x8*)&bb[rb * 64 + ch];
      }
      #pragma unroll
      for (int mi = 0; mi < 4; ++mi)
        #pragma unroll
        for (int ni = 0; ni < 4; ++ni)
          acc[mi][ni] = __builtin_amdgcn_mfma_f32_16x16x32_bf16(af[mi], bf[ni], acc[mi][ni], 0, 0, 0);
    }
    __builtin_amdgcn_sched_barrier(0);
    __builtin_amdgcn_s_barrier();                        // buf[cur] free for t+2
  }
  const int r4 = g4 * 4;
  #pragma unroll
  for (int mi = 0; mi < 4; ++mi)
    #pragma unroll
    for (int ni = 0; ni < 4; ++ni)
      #pragma unroll
      for (int r = 0; r < 4; ++r) {
        int row = bm + wm + mi * 16 + r4 + r;
        int col = bn + wn + ni * 16 + l16;
        float v = acc[mi][ni][r];
        if (resid) v += resid[(size_t)row * N + col];
        C[(size_t)row * N + col] = v;
      }
}

// ---------------------------------------------------------------------------
// Expert-batched MoE GEMM, same pipeline, optional row gather; invalid rows
// stage from a zero page.
// ---------------------------------------------------------------------------
__global__ __launch_bounds__(256) void gemm_moe_bb(
    const unsigned short* __restrict__ A, const unsigned short* __restrict__ BTall,
    float* __restrict__ C,
    const int* __restrict__ counts, const int* __restrict__ offsets,
    const int* __restrict__ pair_token, const unsigned short* __restrict__ zbuf,
    int gather, int K, int N)
{
  const int e = blockIdx.z;
  const int cnt = counts[e];
  const int bm = blockIdx.x * 128;
  if (bm >= cnt) return;
  const int base = offsets[e];
  const int bn = blockIdx.y * 128;
  __shared__ unsigned short As[2][128 * 64];
  __shared__ unsigned short Bs[2][128 * 64];
  const int tid = threadIdx.x, lane = tid & 63, wid = tid >> 6;
  const int wm = (wid >> 1) * 64, wn = (wid & 1) * 64;
  const int l16 = lane & 15, g4 = lane >> 4;
  const int rseg = lane >> 3;
  const int csw  = ((lane & 7) ^ rseg) * 8;
  const unsigned short* BT = BTall + (size_t)e * N * K;
  const unsigned short* aSrc[4];
  const unsigned short* bSrc[4];
  int aOk[4];
  #pragma unroll
  for (int p = 0; p < 4; ++p) {
    int row = (p * 4 + wid) * 8 + rseg;
    int lr = bm + row;
    int tok = -1;
    if (lr < cnt) tok = gather ? pair_token[base + lr] : base + lr;
    aOk[p] = (tok >= 0);
    aSrc[p] = aOk[p] ? (A + (size_t)tok * K + csw) : (zbuf + csw);
    bSrc[p] = BT + (size_t)(bn + row) * K + csw;
  }
  f32x4 acc[4][4] = {};
  const int NT = K >> 6;
  #pragma unroll
  for (int p = 0; p < 4; ++p) glds16(aSrc[p], &As[0][(p * 4 + wid) * 512]);
  #pragma unroll
  for (int p = 0; p < 4; ++p) glds16(bSrc[p], &Bs[0][(p * 4 + wid) * 512]);
  for (int t = 0; t < NT; ++t) {
    const int cur = t & 1;
    if (t + 1 < NT) {
      const int k0 = (t + 1) << 6;
      #pragma unroll
      for (int p = 0; p < 4; ++p)
        glds16(aSrc[p] + (aOk[p] ? k0 : 0), &As[cur ^ 1][(p * 4 + wid) * 512]);
      #pragma unroll
      for (int p = 0; p < 4; ++p)
        glds16(bSrc[p] + k0, &Bs[cur ^ 1][(p * 4 + wid) * 512]);
      asm volatile("s_waitcnt vmcnt(8)" ::: "memory");
    } else {
      asm volatile("s_waitcnt vmcnt(0)" ::: "memory");
    }
    __builtin_amdgcn_s_barrier();
    __builtin_amdgcn_sched_barrier(0);
    const unsigned short* ab = &As[cur][0];
    const unsigned short* bb = &Bs[cur][0];
    #pragma unroll
    for (int ks = 0; ks < 2; ++ks) {
      bf16x8 af[4], bf[4];
      #pragma unroll
      for (int i = 0; i < 4; ++i) {
        int ra = wm + i * 16 + l16;
        int rb = wn + i * 16 + l16;
        int ch = ((ks * 4 + g4) ^ (l16 & 7)) * 8;
        af[i] = *(const bf16x8*)&ab[ra * 64 + ch];
        bf[i] = *(const bf16x8*)&bb[rb * 64 + ch];
      }
      #pragma unroll
      for (int mi = 0; mi < 4; ++mi)
        #pragma unroll
        for (int ni = 0; ni < 4; ++ni)
          acc[mi][ni] = __builtin_amdgcn_mfma_f32_16x16x32_bf16(af[mi], bf[ni], acc[mi][ni], 0, 0, 0);
    }
    __builtin_amdgcn_sched_barrier(0);
    __builtin_amdgcn_s_barrier();
  }
  const int r4 = g4 * 4;
  #pragma unroll
  for (int mi = 0; mi < 4; ++mi)
    #pragma unroll
    for (int ni = 0; ni < 4; ++ni)
      #pragma unroll
      for (int r = 0; r < 4; ++r) {
        int lrow = bm + wm + mi * 16 + r4 + r;
        int col  = bn + wn + ni * 16 + l16;
        if (lrow < cnt)
          C[(size_t)(base + lrow) * N + col] = acc[mi][ni][r];
      }
}

// ---------------------------------------------------------------------------
// RMSNorm over D=2048, f32 in -> bf16 out (+ optional exact f32 out).
// ---------------------------------------------------------------------------
__global__ __launch_bounds__(256) void rmsnorm_rows(
    const float* __restrict__ in, const float* __restrict__ w,
    unsigned short* __restrict__ out, float* __restrict__ out32)
{
  const int row = blockIdx.x;
  const int tid = threadIdx.x;
  const float* x = in + (size_t)row * 2048;
  float4 a = *(const float4*)&x[tid * 8];
  float4 b = *(const float4*)&x[tid * 8 + 4];
  float s = a.x*a.x + a.y*a.y + a.z*a.z + a.w*a.w
          + b.x*b.x + b.y*b.y + b.z*b.z + b.w*b.w;
  #pragma unroll
  for (int off = 1; off < 64; off <<= 1) s += __shfl_xor(s, off);
  __shared__ float red[4];
  if ((tid & 63) == 0) red[tid >> 6] = s;
  __syncthreads();
  float inv = rsqrtf((red[0] + red[1] + red[2] + red[3]) * (1.f / 2048.f) + 1e-6f);
  float4 wa = *(const float4*)&w[tid * 8];
  float4 wb = *(const float4*)&w[tid * 8 + 4];
  float y[8] = {a.x * inv * wa.x, a.y * inv * wa.y, a.z * inv * wa.z, a.w * inv * wa.w,
                b.x * inv * wb.x, b.y * inv * wb.y, b.z * inv * wb.z, b.w * inv * wb.w};
  unsigned short* o = out + (size_t)row * 2048 + tid * 8;
  #pragma unroll
  for (int j = 0; j < 8; ++j) o[j] = f2bf(y[j]);
  if (out32) {
    float* o32 = out32 + (size_t)row * 2048 + tid * 8;
    *(float4*)&o32[0] = make_float4(y[0], y[1], y[2], y[3]);
    *(float4*)&o32[4] = make_float4(y[4], y[5], y[6], y[7]);
  }
}

__global__ __launch_bounds__(256) void f32_to_bf16_k(
    const float* __restrict__ in, unsigned short* __restrict__ out, int n)
{
  int i = (blockIdx.x * 256 + threadIdx.x) * 4;
  if (i + 3 < n) {
    float4 v = *(const float4*)&in[i];
    out[i + 0] = f2bf(v.x); out[i + 1] = f2bf(v.y);
    out[i + 2] = f2bf(v.z); out[i + 3] = f2bf(v.w);
  }
}

// ---------------------------------------------------------------------------
// Per-(b,s,h) head RMSNorm + RoPE, relayout to (B, NH, seq_total, 128) bf16.
// ---------------------------------------------------------------------------
__global__ __launch_bounds__(256) void qk_norm_rope(
    const float* __restrict__ raw, int ld, const float* __restrict__ nw,
    const float* __restrict__ cosT, const float* __restrict__ sinT,
    unsigned short* __restrict__ out,
    int S, int NH, int seq_total, int s_off, float premul)
{
  int rowid = blockIdx.x * 4 + (threadIdx.x >> 6);
  int lane  = threadIdx.x & 63;
  int b = rowid / (S * NH);
  int rem = rowid % (S * NH);
  int s = rem / NH, h = rem % NH;
  const float* src = raw + (size_t)(b * S + s) * ld + h * 128;
  float2 xv = *(const float2*)&src[lane * 2];
  float ss = xv.x * xv.x + xv.y * xv.y;
  #pragma unroll
  for (int off = 1; off < 64; off <<= 1) ss += __shfl_xor(ss, off);
  float inv = rsqrtf(ss * (1.f / 128.f) + 1e-6f);
  float yr = xv.x * inv * nw[lane * 2];
  float yi = xv.y * inv * nw[lane * 2 + 1];
  float c  = cosT[s * 64 + lane], sn = sinT[s * 64 + lane];
  float orr = (yr * c - yi * sn) * premul;
  float oi  = (yr * sn + yi * c) * premul;
  unsigned short* dst = out + ((size_t)(b * NH + h) * seq_total + (s + s_off)) * 128;
  dst[lane * 2]     = f2bf(orr);
  dst[lane * 2 + 1] = f2bf(oi);
}

__global__ __launch_bounds__(256) void v_relayout(
    const float* __restrict__ raw, int ld, unsigned short* __restrict__ out,
    int S, int NH, int seq_total, int s_off)
{
  int rowid = blockIdx.x * 4 + (threadIdx.x >> 6);
  int lane  = threadIdx.x & 63;
  int b = rowid / (S * NH);
  int rem = rowid % (S * NH);
  int s = rem / NH, h = rem % NH;
  const float* src = raw + (size_t)(b * S + s) * ld + h * 128;
  float2 xv = *(const float2*)&src[lane * 2];
  unsigned short* dst = out + ((size_t)(b * NH + h) * seq_total + (s + s_off)) * 128;
  dst[lane * 2]     = f2bf(xv.x);
  dst[lane * 2 + 1] = f2bf(xv.y);
}

// ---------------------------------------------------------------------------
// Flash attention: 64 q-rows per block (4 waves x 16 rows), Sk tiles of 64.
// ---------------------------------------------------------------------------
__global__ __launch_bounds__(256) void attn_kernel(
    const unsigned short* __restrict__ q,    // (B,16,1024,128)
    const unsigned short* __restrict__ kbuf, // (B,4,1536,128)
    const unsigned short* __restrict__ vbuf, // (B,4,1536,128)
    unsigned short* __restrict__ o)          // (B*1024, 2048)
{
  const int SK = 1536;
  const int bh = blockIdx.y;
  const int b = bh >> 4, h = bh & 15, kvh = h >> 2;
  const int q0 = blockIdx.x * 64;
  const int tid = threadIdx.x, lane = tid & 63, wid = tid >> 6;
  const int l16 = lane & 15, kb = (lane >> 4) * 8, r4 = (lane >> 4) * 4;
  __shared__ unsigned short Ks[64][136];
  __shared__ unsigned short VT[128][72];
  __shared__ unsigned short Ps[4][16][72];
  const unsigned short* qrow =
      q + ((size_t)(b * 16 + h) * 1024 + q0 + wid * 16 + l16) * 128;
  bf16x8 qf[4];
  #pragma unroll
  for (int ks = 0; ks < 4; ++ks) qf[ks] = *(const bf16x8*)&qrow[ks * 32 + kb];
  float mrow[4] = {-1e30f, -1e30f, -1e30f, -1e30f};
  float lrow[4] = {0.f, 0.f, 0.f, 0.f};
  f32x4 oacc[8] = {};
  const unsigned short* kb_base = kbuf + (size_t)(b * 4 + kvh) * SK * 128;
  const unsigned short* vb_base = vbuf + (size_t)(b * 4 + kvh) * SK * 128;
  for (int kt = 0; kt < SK; kt += 64) {
    __syncthreads();
    #pragma unroll
    for (int c = tid; c < 1024; c += 256) {
      int r = c >> 4, cc = (c & 15) * 8;
      *(u16x8*)&Ks[r][cc] = *(const u16x8*)&kb_base[(size_t)(kt + r) * 128 + cc];
    }
    #pragma unroll
    for (int c = tid; c < 1024; c += 256) {
      int r = c >> 4, cc = (c & 15) * 8;
      u16x8 v = *(const u16x8*)&vb_base[(size_t)(kt + r) * 128 + cc];
      #pragma unroll
      for (int j = 0; j < 8; ++j) VT[cc + j][r] = v[j];
    }
    __syncthreads();
    f32x4 sacc[4] = {};
    #pragma unroll
    for (int ks = 0; ks < 4; ++ks) {
      #pragma unroll
      for (int ni = 0; ni < 4; ++ni) {
        bf16x8 kf = *(const bf16x8*)&Ks[ni * 16 + l16][ks * 32 + kb];
        sacc[ni] = __builtin_amdgcn_mfma_f32_16x16x32_bf16(qf[ks], kf, sacc[ni], 0, 0, 0);
      }
    }
    float pv[4][4], alpha[4];
    #pragma unroll
    for (int r = 0; r < 4; ++r) {
      float tm = fmaxf(fmaxf(sacc[0][r], sacc[1][r]), fmaxf(sacc[2][r], sacc[3][r]));
      #pragma unroll
      for (int off = 1; off < 16; off <<= 1) tm = fmaxf(tm, __shfl_xor(tm, off));
      float mn = fmaxf(mrow[r], tm);
      alpha[r] = __expf(mrow[r] - mn);
      float s = 0.f;
      #pragma unroll
      for (int ni = 0; ni < 4; ++ni) {
        float p = __expf(sacc[ni][r] - mn);
        pv[ni][r] = p; s += p;
      }
      #pragma unroll
      for (int off = 1; off < 16; off <<= 1) s += __shfl_xor(s, off);
      lrow[r] = lrow[r] * alpha[r] + s;
      mrow[r] = mn;
    }
    #pragma unroll
    for (int ni = 0; ni < 8; ++ni)
      #pragma unroll
      for (int r = 0; r < 4; ++r) oacc[ni][r] *= alpha[r];
    #pragma unroll
    for (int ni = 0; ni < 4; ++ni)
      #pragma unroll
      for (int r = 0; r < 4; ++r)
        Ps[wid][r4 + r][ni * 16 + l16] = f2bf(pv[ni][r]);
    asm volatile("s_waitcnt lgkmcnt(0)" ::: "memory");
    __builtin_amdgcn_sched_barrier(0);
    #pragma unroll
    for (int ks = 0; ks < 2; ++ks) {
      bf16x8 pf = *(const bf16x8*)&Ps[wid][l16][ks * 32 + kb];
      #pragma unroll
      for (int ni = 0; ni < 8; ++ni) {
        bf16x8 vf = *(const bf16x8*)&VT[ni * 16 + l16][ks * 32 + kb];
        oacc[ni] = __builtin_amdgcn_mfma_f32_16x16x32_bf16(pf, vf, oacc[ni], 0, 0, 0);
      }
    }
  }
  #pragma unroll
  for (int ni = 0; ni < 8; ++ni)
    #pragma unroll
    for (int r = 0; r < 4; ++r) {
      float val = oacc[ni][r] / lrow[r];
      size_t row = (size_t)b * 1024 + q0 + wid * 16 + r4 + r;
      o[row * 2048 + h * 128 + ni * 16 + l16] = f2bf(val);
    }
}

// ---------------------------------------------------------------------------
// Router: one wave per token, f32 input (exact), f32 accumulate.
// ---------------------------------------------------------------------------
__global__ __launch_bounds__(64) void router_kernel(
    const float* __restrict__ xt32, const float* __restrict__ rw,
    int* __restrict__ topi, float* __restrict__ topw, int* __restrict__ counts)
{
  int t = blockIdx.x, lane = threadIdx.x;
  float acc[8] = {};
  const float* x = xt32 + (size_t)t * 2048;
  for (int d0 = lane * 4; d0 < 2048; d0 += 256) {
    float4 xv = *(const float4*)&x[d0];
    float xa[4] = {xv.x, xv.y, xv.z, xv.w};
    #pragma unroll
    for (int j = 0; j < 4; ++j) {
      const float4 r0 = *(const float4*)&rw[(d0 + j) * 8];
      const float4 r1 = *(const float4*)&rw[(d0 + j) * 8 + 4];
      acc[0] += xa[j] * r0.x; acc[1] += xa[j] * r0.y;
      acc[2] += xa[j] * r0.z; acc[3] += xa[j] * r0.w;
      acc[4] += xa[j] * r1.x; acc[5] += xa[j] * r1.y;
      acc[6] += xa[j] * r1.z; acc[7] += xa[j] * r1.w;
    }
  }
  #pragma unroll
  for (int e = 0; e < 8; ++e)
    #pragma unroll
    for (int off = 1; off < 64; off <<= 1) acc[e] += __shfl_xor(acc[e], off);
  if (lane == 0) {
    float v0 = acc[0]; int e0 = 0;
    #pragma unroll
    for (int e = 1; e < 8; ++e) if (acc[e] > v0) { v0 = acc[e]; e0 = e; }
    float v1 = -1e30f; int e1 = 0;
    #pragma unroll
    for (int e = 0; e < 8; ++e) if (e != e0 && acc[e] > v1) { v1 = acc[e]; e1 = e; }
    float x1 = expf(v1 - v0);
    float w0 = 1.f / (1.f + x1);
    float w1 = x1 / (1.f + x1);
    topi[2 * t] = e0; topi[2 * t + 1] = e1;
    topw[2 * t] = w0; topw[2 * t + 1] = w1;
    atomicAdd(&counts[e0], 1);
    atomicAdd(&counts[e1], 1);
  }
}

__global__ void scan_offsets(const int* __restrict__ counts, int* __restrict__ offsets)
{
  if (threadIdx.x == 0 && blockIdx.x == 0) {
    int a = 0;
    for (int e = 0; e < 8; ++e) { offsets[e] = a; a += counts[e]; }
    offsets[8] = a;
  }
}

__global__ __launch_bounds__(256) void scatter_pairs(
    const int* __restrict__ topi, const int* __restrict__ offsets,
    int* __restrict__ fill, int* __restrict__ pair_token, int* __restrict__ token_slot)
{
  int t = blockIdx.x * 256 + threadIdx.x;
  if (t >= 2048) return;
  #pragma unroll
  for (int k = 0; k < 2; ++k) {
    int e = topi[2 * t + k];
    int slot = offsets[e] + atomicAdd(&fill[e], 1);
    pair_token[slot] = t;
    token_slot[2 * t + k] = slot;
  }
}

__global__ __launch_bounds__(256) void act_silu(
    const float* __restrict__ gu, unsigned short* __restrict__ act)
{
  int p = blockIdx.x;
  int c = threadIdx.x * 4;
  float4 g = *(const float4*)&gu[(size_t)p * 2048 + c];
  float4 u = *(const float4*)&gu[(size_t)p * 2048 + 1024 + c];
  float gg[4] = {g.x, g.y, g.z, g.w};
  float uu[4] = {u.x, u.y, u.z, u.w};
  #pragma unroll
  for (int j = 0; j < 4; ++j) {
    float a = gg[j] / (1.f + __expf(-gg[j])) * uu[j];
    act[(size_t)p * 1024 + c + j] = f2bf(a);
  }
}

__global__ __launch_bounds__(256) void moe_combine(
    float* __restrict__ out, const float* __restrict__ eo,
    const int* __restrict__ token_slot, const float* __restrict__ topw)
{
  int t = blockIdx.x;
  int c = threadIdx.x * 8;
  int s0 = token_slot[2 * t], s1 = token_slot[2 * t + 1];
  float w0 = topw[2 * t], w1 = topw[2 * t + 1];
  #pragma unroll
  for (int j0 = 0; j0 < 8; j0 += 4) {
    float4 a = *(const float4*)&eo[(size_t)s0 * 2048 + c + j0];
    float4 b = *(const float4*)&eo[(size_t)s1 * 2048 + c + j0];
    float4 v = *(const float4*)&out[(size_t)t * 2048 + c + j0];
    v.x += w0 * a.x + w1 * b.x;
    v.y += w0 * a.y + w1 * b.y;
    v.z += w0 * a.z + w1 * b.z;
    v.w += w0 * a.w + w1 * b.w;
    *(float4*)&out[(size_t)t * 2048 + c + j0] = v;
  }
}

// ---------------------------------------------------------------------------
extern "C" void kernel_launch(void* const* d_in, const int* in_sizes, int n_in,
                              void* d_out, int out_size, void* d_ws, size_t ws_size,
                              hipStream_t stream)
{
  const float* hidden  = (const float*)d_in[0];
  const float* enc     = (const float*)d_in[1];
  const float* img_cos = (const float*)d_in[2];
  const float* img_sin = (const float*)d_in[3];
  const float* txt_cos = (const float*)d_in[4];
  const float* txt_sin = (const float*)d_in[5];
  const float* norm1_w = (const float*)d_in[6];
  const float* norm2_w = (const float*)d_in[7];
  const float* wq      = (const float*)d_in[8];
  const float* wk      = (const float*)d_in[9];
  const float* wv      = (const float*)d_in[10];
  const float* wk_txt  = (const float*)d_in[11];
  const float* wv_txt  = (const float*)d_in[12];
  const float* wo      = (const float*)d_in[13];
  const float* q_norm_w       = (const float*)d_in[14];
  const float* k_norm_w       = (const float*)d_in[15];
  const float* added_k_norm_w = (const float*)d_in[16];
  const float* router_w       = (const float*)d_in[17];
  const float* gate_up_proj   = (const float*)d_in[18];
  const float* down_proj      = (const float*)d_in[19];
  float* out = (float*)d_out;

  char* ws = (char*)d_ws;
  size_t off = 0;
  auto alloc = [&](size_t bytes) {
    void* p = ws + off;
    off += (bytes + 255) & ~(size_t)255;
    return p;
  };
  // --- bf16 transposed weights ---
  unsigned short* wqkvT  = (unsigned short*)alloc(3072ULL * 2048 * 2); // q|k|v rows
  unsigned short* wkvtT  = (unsigned short*)alloc(1024ULL * 2048 * 2); // k_txt|v_txt
  unsigned short* woT    = (unsigned short*)alloc(2048ULL * 2048 * 2);
  unsigned short* gupT   = (unsigned short*)alloc(8ULL * 2048 * 2048 * 2);
  unsigned short* dnT    = (unsigned short*)alloc(8ULL * 2048 * 1024 * 2);
  // --- activations ---
  unsigned short* x_bf   = (unsigned short*)alloc(2048ULL * 2048 * 2);
  unsigned short* enc_bf = (unsigned short*)alloc(1024ULL * 2048 * 2);
  float* qkvC = (float*)alloc(4096ULL * 2048 * 4); // [2048][3072] early; gu [4096][2048] late
  float* gu   = qkvC;                              // alias (disjoint lifetimes)
  float* kvtC = (float*)alloc(1024ULL * 1024 * 4); // [1024][1024] k_txt|v_txt
  unsigned short* qb   = (unsigned short*)alloc(2048ULL * 2048 * 2);
  unsigned short* kbuf = (unsigned short*)alloc(2ULL * 4 * 1536 * 128 * 2);
  unsigned short* vbuf = (unsigned short*)alloc(2ULL * 4 * 1536 * 128 * 2);
  unsigned short* obuf = (unsigned short*)alloc(2048ULL * 2048 * 2);
  unsigned short* act  = obuf;                     // alias (obuf dead after wo GEMM)
  unsigned short* xt   = (unsigned short*)alloc(2048ULL * 2048 * 2);
  float* xt32 = (float*)alloc(2048ULL * 2048 * 4);
  int*   ctrl  = (int*)alloc(64 * sizeof(int));    // counts[8] fill[8] offsets[9]
  int*   topi  = (int*)alloc(4096 * 4);
  float* topw  = (float*)alloc(4096 * 4);
  int*   tslot = (int*)alloc(4096 * 4);
  int*   ptok  = (int*)alloc(4096 * 4);
  unsigned short* zbuf = (unsigned short*)alloc(256);
  int* counts = ctrl, * fill = ctrl + 8, * offsets = ctrl + 16;

  hipMemsetAsync(ctrl, 0, 64, stream);
  hipMemsetAsync(zbuf, 0, 256, stream);

  const float scale = 0.08838834764831845f;  // 1/sqrt(128)

  // --- weight preprocessing: f32 [K][N] -> bf16 [N][K] ---
  convert_w<<<dim3(32, 32, 1), 256, 0, stream>>>(wq,     wqkvT,                    2048, 2048);
  convert_w<<<dim3(32,  8, 1), 256, 0, stream>>>(wk,     wqkvT + 2048ULL * 2048,   2048, 512);
  convert_w<<<dim3(32,  8, 1), 256, 0, stream>>>(wv,     wqkvT + 2560ULL * 2048,   2048, 512);
  convert_w<<<dim3(32,  8, 1), 256, 0, stream>>>(wk_txt, wkvtT,                    2048, 512);
  convert_w<<<dim3(32,  8, 1), 256, 0, stream>>>(wv_txt, wkvtT + 512ULL * 2048,    2048, 512);
  convert_w<<<dim3(32, 32, 1), 256, 0, stream>>>(wo,     woT,                      2048, 2048);
  convert_w<<<dim3(32, 32, 8), 256, 0, stream>>>(gate_up_proj, gupT,               2048, 2048);
  convert_w<<<dim3(16, 32, 8), 256, 0, stream>>>(down_proj,    dnT,                1024, 2048);

  rmsnorm_rows<<<2048, 256, 0, stream>>>(hidden, norm1_w, x_bf, nullptr);
  f32_to_bf16_k<<<2048, 256, 0, stream>>>(enc, enc_bf, 1024 * 2048);

  // fused qkv projection: [2048][2048] @ [3072][2048]^T -> [2048][3072]
  gemm_bb<<<dim3(16, 24), 256, 0, stream>>>(x_bf, wqkvT, qkvC, nullptr, 2048, 3072, 2048);
  // fused k/v txt projection: [1024][2048] @ [1024][2048]^T -> [1024][1024]
  gemm_bb<<<dim3(8, 8), 256, 0, stream>>>(enc_bf, wkvtT, kvtC, nullptr, 1024, 1024, 2048);

  qk_norm_rope<<<8192, 256, 0, stream>>>(qkvC, 3072, q_norm_w, img_cos, img_sin, qb,
                                         1024, 16, 1024, 0, scale);
  qk_norm_rope<<<2048, 256, 0, stream>>>(qkvC + 2048, 3072, k_norm_w, img_cos, img_sin, kbuf,
                                         1024, 4, 1536, 0, 1.0f);
  qk_norm_rope<<<1024, 256, 0, stream>>>(kvtC, 1024, added_k_norm_w, txt_cos, txt_sin, kbuf,
                                         512, 4, 1536, 1024, 1.0f);
  v_relayout<<<2048, 256, 0, stream>>>(qkvC + 2560, 3072, vbuf, 1024, 4, 1536, 0);
  v_relayout<<<1024, 256, 0, stream>>>(kvtC + 512, 1024, vbuf, 512, 4, 1536, 1024);

  attn_kernel<<<dim3(16, 32), 256, 0, stream>>>(qb, kbuf, vbuf, obuf);

  gemm_bb<<<dim3(16, 16), 256, 0, stream>>>(obuf, woT, out, hidden, 2048, 2048, 2048);

  rmsnorm_rows<<<2048, 256, 0, stream>>>(out, norm2_w, xt, xt32);
  router_kernel<<<2048, 64, 0, stream>>>(xt32, router_w, topi, topw, counts);
  scan_offsets<<<1, 64, 0, stream>>>(counts, offsets);
  scatter_pairs<<<8, 256, 0, stream>>>(topi, offsets, fill, ptok, tslot);

  gemm_moe_bb<<<dim3(16, 16, 8), 256, 0, stream>>>(xt, gupT, gu,
                                                   counts, offsets, ptok, zbuf, 1, 2048, 2048);
  act_silu<<<4096, 256, 0, stream>>>(gu, act);
  gemm_moe_bb<<<dim3(16, 16, 8), 256, 0, stream>>>(act, dnT, gu,
                                                   counts, offsets, ptok, zbuf, 0, 1024, 2048);
  moe_combine<<<2048, 256, 0, stream>>>(out, gu, tslot, topw);
}

// Round 7
// 702.110 us; speedup vs baseline: 1.2185x; 1.1686x over previous
//
#include <hip/hip_runtime.h>

// ---------------------------------------------------------------------------
// NucleusMoEImageTransformerBlock round 7.
// B=2 SI=1024 ST=512 D=2048 H=16 KV=4 HD=128 E=8 F=1024 TOPK=2
// Round-7: T1 XCD-aware bijective block swizzle (m204) on all GEMMs and
// attention. 1D grids, bm-fastest work order; MoE chunking maps one expert
// per XCD (weights stream once per L2, A-rows L2-resident). GEMM inner
// pipeline unchanged from r6 (counted-vmcnt dbuf, XOR chunk swizzle).
// ---------------------------------------------------------------------------

typedef __attribute__((ext_vector_type(8))) __bf16 bf16x8;
typedef __attribute__((ext_vector_type(8))) unsigned short u16x8;
typedef __attribute__((ext_vector_type(4))) float f32x4;

__device__ __forceinline__ unsigned short f2bf(float x) {
  unsigned u = __builtin_bit_cast(unsigned, x);
  u += 0x7fffu + ((u >> 16) & 1u);        // RNE
  return (unsigned short)(u >> 16);
}
__device__ __forceinline__ float bf2f(unsigned short b) {
  return __builtin_bit_cast(float, ((unsigned)b) << 16);
}

__device__ __forceinline__ void glds16(const unsigned short* g, unsigned short* l) {
  __builtin_amdgcn_global_load_lds(
      (const __attribute__((address_space(1))) void*)g,
      (__attribute__((address_space(3))) void*)l, 16, 0, 0);
}

// m204 bijective XCD chunk swizzle: HW index -> work index such that
// consecutive work ids land on the same XCD in contiguous chunks.
__device__ __forceinline__ int xcd_swz(int orig, int nwg) {
  int q = nwg >> 3, r = nwg & 7;
  int xcd = orig & 7, idx = orig >> 3;
  int base = (xcd < r) ? xcd * (q + 1) : r * (q + 1) + (xcd - r) * q;
  return base + idx;
}

// ---------------------------------------------------------------------------
// Weight convert+transpose: W f32 [K][N] -> WT bf16 [N][K].
// ---------------------------------------------------------------------------
__global__ __launch_bounds__(256) void convert_w(
    const float* __restrict__ W, unsigned short* __restrict__ WT,
    int K, int N)
{
  __shared__ unsigned short T[64][66];
  const float* Wz = W + (size_t)blockIdx.z * K * N;
  unsigned short* WTz = WT + (size_t)blockIdx.z * K * N;
  const int k0 = blockIdx.x * 64, n0 = blockIdx.y * 64;
  const int tid = threadIdx.x;
  #pragma unroll
  for (int i = tid; i < 64 * 16; i += 256) {
    int k = i >> 4, n4 = (i & 15) * 4;
    float4 v = *(const float4*)&Wz[(size_t)(k0 + k) * N + n0 + n4];
    T[n4 + 0][k] = f2bf(v.x);
    T[n4 + 1][k] = f2bf(v.y);
    T[n4 + 2][k] = f2bf(v.z);
    T[n4 + 3][k] = f2bf(v.w);
  }
  __syncthreads();
  #pragma unroll
  for (int i = tid; i < 64 * 8; i += 256) {
    int n = i >> 3, k8 = (i & 7) * 8;
    *(u16x8*)&WTz[(size_t)(n0 + n) * K + k0 + k8] = *(const u16x8*)&T[n][k8];
  }
}

// ---------------------------------------------------------------------------
// Dense GEMM: C[M,N] = A[M,K] @ BT[N,K]^T (+resid). bf16 in, f32 out.
// 1D grid, XCD-swizzled, bm-fastest. Counted-vmcnt dbuf pipeline.
// ---------------------------------------------------------------------------
__global__ __launch_bounds__(256) void gemm_bb(
    const unsigned short* __restrict__ A, const unsigned short* __restrict__ BT,
    float* __restrict__ C, const float* __restrict__ resid,
    int M, int N, int K)
{
  __shared__ unsigned short As[2][128 * 64];
  __shared__ unsigned short Bs[2][128 * 64];
  const int mb = M >> 7;
  const int w = xcd_swz(blockIdx.x, gridDim.x);
  const int bm = (w % mb) * 128, bn = (w / mb) * 128;
  const int tid = threadIdx.x, lane = tid & 63, wid = tid >> 6;
  const int wm = (wid >> 1) * 64, wn = (wid & 1) * 64;
  const int l16 = lane & 15, g4 = lane >> 4;
  const int rseg = lane >> 3;                    // 0..7 row within segment
  const int csw  = ((lane & 7) ^ rseg) * 8;      // swizzled src col (shorts)
  const unsigned short* aSrc[4];
  const unsigned short* bSrc[4];
  #pragma unroll
  for (int p = 0; p < 4; ++p) {
    int row = (p * 4 + wid) * 8 + rseg;
    aSrc[p] = A  + (size_t)(bm + row) * K + csw;
    bSrc[p] = BT + (size_t)(bn + row) * K + csw;
  }
  f32x4 acc[4][4] = {};
  const int NT = K >> 6;
  #pragma unroll
  for (int p = 0; p < 4; ++p) glds16(aSrc[p], &As[0][(p * 4 + wid) * 512]);
  #pragma unroll
  for (int p = 0; p < 4; ++p) glds16(bSrc[p], &Bs[0][(p * 4 + wid) * 512]);
  for (int t = 0; t < NT; ++t) {
    const int cur = t & 1;
    if (t + 1 < NT) {
      const int k0 = (t + 1) << 6;
      #pragma unroll
      for (int p = 0; p < 4; ++p) glds16(aSrc[p] + k0, &As[cur ^ 1][(p * 4 + wid) * 512]);
      #pragma unroll
      for (int p = 0; p < 4; ++p) glds16(bSrc[p] + k0, &Bs[cur ^ 1][(p * 4 + wid) * 512]);
      asm volatile("s_waitcnt vmcnt(8)" ::: "memory");  // own tile-t done; t+1 in flight
    } else {
      asm volatile("s_waitcnt vmcnt(0)" ::: "memory");
    }
    __builtin_amdgcn_s_barrier();
    __builtin_amdgcn_sched_barrier(0);
    const unsigned short* ab = &As[cur][0];
    const unsigned short* bb = &Bs[cur][0];
    #pragma unroll
    for (int ks = 0; ks < 2; ++ks) {
      bf16x8 af[4], bf[4];
      #pragma unroll
      for (int i = 0; i < 4; ++i) {
        int ra = wm + i * 16 + l16;
        int rb = wn + i * 16 + l16;
        int ch = ((ks * 4 + g4) ^ (l16 & 7)) * 8;
        af[i] = *(const bf16x8*)&ab[ra * 64 + ch];
        bf[i] = *(const bf16x8*)&bb[rb * 64 + ch];
      }
      #pragma unroll
      for (int mi = 0; mi < 4; ++mi)
        #pragma unroll
        for (int ni = 0; ni < 4; ++ni)
          acc[mi][ni] = __builtin_amdgcn_mfma_f32_16x16x32_bf16(af[mi], bf[ni], acc[mi][ni], 0, 0, 0);
    }
    __builtin_amdgcn_sched_barrier(0);
    __builtin_amdgcn_s_barrier();
  }
  const int r4 = g4 * 4;
  #pragma unroll
  for (int mi = 0; mi < 4; ++mi)
    #pragma unroll
    for (int ni = 0; ni < 4; ++ni)
      #pragma unroll
      for (int r = 0; r < 4; ++r) {
        int row = bm + wm + mi * 16 + r4 + r;
        int col = bn + wn + ni * 16 + l16;
        float v = acc[mi][ni][r];
        if (resid) v += resid[(size_t)row * N + col];
        C[(size_t)row * N + col] = v;
      }
}

// ---------------------------------------------------------------------------
// Expert-batched MoE GEMM. 1D grid 2048 = 16 bm x 16 bn x 8 e, XCD-swizzled
// so each XCD owns one expert. Optional row gather; invalid rows use zbuf.
// ---------------------------------------------------------------------------
__global__ __launch_bounds__(256) void gemm_moe_bb(
    const unsigned short* __restrict__ A, const unsigned short* __restrict__ BTall,
    float* __restrict__ C,
    const int* __restrict__ counts, const int* __restrict__ offsets,
    const int* __restrict__ pair_token, const unsigned short* __restrict__ zbuf,
    int gather, int K, int N)
{
  const int w = xcd_swz(blockIdx.x, gridDim.x);
  const int e = w >> 8;                 // w / 256
  const int cnt = counts[e];
  const int bm = (w & 15) * 128;
  if (bm >= cnt) return;
  const int base = offsets[e];
  const int bn = ((w >> 4) & 15) * 128;
  __shared__ unsigned short As[2][128 * 64];
  __shared__ unsigned short Bs[2][128 * 64];
  const int tid = threadIdx.x, lane = tid & 63, wid = tid >> 6;
  const int wm = (wid >> 1) * 64, wn = (wid & 1) * 64;
  const int l16 = lane & 15, g4 = lane >> 4;
  const int rseg = lane >> 3;
  const int csw  = ((lane & 7) ^ rseg) * 8;
  const unsigned short* BT = BTall + (size_t)e * N * K;
  const unsigned short* aSrc[4];
  const unsigned short* bSrc[4];
  int aOk[4];
  #pragma unroll
  for (int p = 0; p < 4; ++p) {
    int row = (p * 4 + wid) * 8 + rseg;
    int lr = bm + row;
    int tok = -1;
    if (lr < cnt) tok = gather ? pair_token[base + lr] : base + lr;
    aOk[p] = (tok >= 0);
    aSrc[p] = aOk[p] ? (A + (size_t)tok * K + csw) : (zbuf + csw);
    bSrc[p] = BT + (size_t)(bn + row) * K + csw;
  }
  f32x4 acc[4][4] = {};
  const int NT = K >> 6;
  #pragma unroll
  for (int p = 0; p < 4; ++p) glds16(aSrc[p], &As[0][(p * 4 + wid) * 512]);
  #pragma unroll
  for (int p = 0; p < 4; ++p) glds16(bSrc[p], &Bs[0][(p * 4 + wid) * 512]);
  for (int t = 0; t < NT; ++t) {
    const int cur = t & 1;
    if (t + 1 < NT) {
      const int k0 = (t + 1) << 6;
      #pragma unroll
      for (int p = 0; p < 4; ++p)
        glds16(aSrc[p] + (aOk[p] ? k0 : 0), &As[cur ^ 1][(p * 4 + wid) * 512]);
      #pragma unroll
      for (int p = 0; p < 4; ++p)
        glds16(bSrc[p] + k0, &Bs[cur ^ 1][(p * 4 + wid) * 512]);
      asm volatile("s_waitcnt vmcnt(8)" ::: "memory");
    } else {
      asm volatile("s_waitcnt vmcnt(0)" ::: "memory");
    }
    __builtin_amdgcn_s_barrier();
    __builtin_amdgcn_sched_barrier(0);
    const unsigned short* ab = &As[cur][0];
    const unsigned short* bb = &Bs[cur][0];
    #pragma unroll
    for (int ks = 0; ks < 2; ++ks) {
      bf16x8 af[4], bf[4];
      #pragma unroll
      for (int i = 0; i < 4; ++i) {
        int ra = wm + i * 16 + l16;
        int rb = wn + i * 16 + l16;
        int ch = ((ks * 4 + g4) ^ (l16 & 7)) * 8;
        af[i] = *(const bf16x8*)&ab[ra * 64 + ch];
        bf[i] = *(const bf16x8*)&bb[rb * 64 + ch];
      }
      #pragma unroll
      for (int mi = 0; mi < 4; ++mi)
        #pragma unroll
        for (int ni = 0; ni < 4; ++ni)
          acc[mi][ni] = __builtin_amdgcn_mfma_f32_16x16x32_bf16(af[mi], bf[ni], acc[mi][ni], 0, 0, 0);
    }
    __builtin_amdgcn_sched_barrier(0);
    __builtin_amdgcn_s_barrier();
  }
  const int r4 = g4 * 4;
  #pragma unroll
  for (int mi = 0; mi < 4; ++mi)
    #pragma unroll
    for (int ni = 0; ni < 4; ++ni)
      #pragma unroll
      for (int r = 0; r < 4; ++r) {
        int lrow = bm + wm + mi * 16 + r4 + r;
        int col  = bn + wn + ni * 16 + l16;
        if (lrow < cnt)
          C[(size_t)(base + lrow) * N + col] = acc[mi][ni][r];
      }
}

// ---------------------------------------------------------------------------
// RMSNorm over D=2048, f32 in -> bf16 out (+ optional exact f32 out).
// ---------------------------------------------------------------------------
__global__ __launch_bounds__(256) void rmsnorm_rows(
    const float* __restrict__ in, const float* __restrict__ w,
    unsigned short* __restrict__ out, float* __restrict__ out32)
{
  const int row = blockIdx.x;
  const int tid = threadIdx.x;
  const float* x = in + (size_t)row * 2048;
  float4 a = *(const float4*)&x[tid * 8];
  float4 b = *(const float4*)&x[tid * 8 + 4];
  float s = a.x*a.x + a.y*a.y + a.z*a.z + a.w*a.w
          + b.x*b.x + b.y*b.y + b.z*b.z + b.w*b.w;
  #pragma unroll
  for (int off = 1; off < 64; off <<= 1) s += __shfl_xor(s, off);
  __shared__ float red[4];
  if ((tid & 63) == 0) red[tid >> 6] = s;
  __syncthreads();
  float inv = rsqrtf((red[0] + red[1] + red[2] + red[3]) * (1.f / 2048.f) + 1e-6f);
  float4 wa = *(const float4*)&w[tid * 8];
  float4 wb = *(const float4*)&w[tid * 8 + 4];
  float y[8] = {a.x * inv * wa.x, a.y * inv * wa.y, a.z * inv * wa.z, a.w * inv * wa.w,
                b.x * inv * wb.x, b.y * inv * wb.y, b.z * inv * wb.z, b.w * inv * wb.w};
  unsigned short* o = out + (size_t)row * 2048 + tid * 8;
  #pragma unroll
  for (int j = 0; j < 8; ++j) o[j] = f2bf(y[j]);
  if (out32) {
    float* o32 = out32 + (size_t)row * 2048 + tid * 8;
    *(float4*)&o32[0] = make_float4(y[0], y[1], y[2], y[3]);
    *(float4*)&o32[4] = make_float4(y[4], y[5], y[6], y[7]);
  }
}

__global__ __launch_bounds__(256) void f32_to_bf16_k(
    const float* __restrict__ in, unsigned short* __restrict__ out, int n)
{
  int i = (blockIdx.x * 256 + threadIdx.x) * 4;
  if (i + 3 < n) {
    float4 v = *(const float4*)&in[i];
    out[i + 0] = f2bf(v.x); out[i + 1] = f2bf(v.y);
    out[i + 2] = f2bf(v.z); out[i + 3] = f2bf(v.w);
  }
}

// ---------------------------------------------------------------------------
// Per-(b,s,h) head RMSNorm + RoPE, relayout to (B, NH, seq_total, 128) bf16.
// ---------------------------------------------------------------------------
__global__ __launch_bounds__(256) void qk_norm_rope(
    const float* __restrict__ raw, int ld, const float* __restrict__ nw,
    const float* __restrict__ cosT, const float* __restrict__ sinT,
    unsigned short* __restrict__ out,
    int S, int NH, int seq_total, int s_off, float premul)
{
  int rowid = blockIdx.x * 4 + (threadIdx.x >> 6);
  int lane  = threadIdx.x & 63;
  int b = rowid / (S * NH);
  int rem = rowid % (S * NH);
  int s = rem / NH, h = rem % NH;
  const float* src = raw + (size_t)(b * S + s) * ld + h * 128;
  float2 xv = *(const float2*)&src[lane * 2];
  float ss = xv.x * xv.x + xv.y * xv.y;
  #pragma unroll
  for (int off = 1; off < 64; off <<= 1) ss += __shfl_xor(ss, off);
  float inv = rsqrtf(ss * (1.f / 128.f) + 1e-6f);
  float yr = xv.x * inv * nw[lane * 2];
  float yi = xv.y * inv * nw[lane * 2 + 1];
  float c  = cosT[s * 64 + lane], sn = sinT[s * 64 + lane];
  float orr = (yr * c - yi * sn) * premul;
  float oi  = (yr * sn + yi * c) * premul;
  unsigned short* dst = out + ((size_t)(b * NH + h) * seq_total + (s + s_off)) * 128;
  dst[lane * 2]     = f2bf(orr);
  dst[lane * 2 + 1] = f2bf(oi);
}

__global__ __launch_bounds__(256) void v_relayout(
    const float* __restrict__ raw, int ld, unsigned short* __restrict__ out,
    int S, int NH, int seq_total, int s_off)
{
  int rowid = blockIdx.x * 4 + (threadIdx.x >> 6);
  int lane  = threadIdx.x & 63;
  int b = rowid / (S * NH);
  int rem = rowid % (S * NH);
  int s = rem / NH, h = rem % NH;
  const float* src = raw + (size_t)(b * S + s) * ld + h * 128;
  float2 xv = *(const float2*)&src[lane * 2];
  unsigned short* dst = out + ((size_t)(b * NH + h) * seq_total + (s + s_off)) * 128;
  dst[lane * 2]     = f2bf(xv.x);
  dst[lane * 2 + 1] = f2bf(xv.y);
}

// ---------------------------------------------------------------------------
// Flash attention: 64 q-rows per block (4 waves x 16 rows), Sk tiles of 64.
// 1D grid 512 = 16 qblk x 32 bh, XCD-swizzled (KV L2-resident per XCD).
// ---------------------------------------------------------------------------
__global__ __launch_bounds__(256) void attn_kernel(
    const unsigned short* __restrict__ q,    // (B,16,1024,128)
    const unsigned short* __restrict__ kbuf, // (B,4,1536,128)
    const unsigned short* __restrict__ vbuf, // (B,4,1536,128)
    unsigned short* __restrict__ o)          // (B*1024, 2048)
{
  const int SK = 1536;
  const int w = xcd_swz(blockIdx.x, gridDim.x);
  const int bh = w >> 4;
  const int b = bh >> 4, h = bh & 15, kvh = h >> 2;
  const int q0 = (w & 15) * 64;
  const int tid = threadIdx.x, lane = tid & 63, wid = tid >> 6;
  const int l16 = lane & 15, kb = (lane >> 4) * 8, r4 = (lane >> 4) * 4;
  __shared__ unsigned short Ks[64][136];
  __shared__ unsigned short VT[128][72];
  __shared__ unsigned short Ps[4][16][72];
  const unsigned short* qrow =
      q + ((size_t)(b * 16 + h) * 1024 + q0 + wid * 16 + l16) * 128;
  bf16x8 qf[4];
  #pragma unroll
  for (int ks = 0; ks < 4; ++ks) qf[ks] = *(const bf16x8*)&qrow[ks * 32 + kb];
  float mrow[4] = {-1e30f, -1e30f, -1e30f, -1e30f};
  float lrow[4] = {0.f, 0.f, 0.f, 0.f};
  f32x4 oacc[8] = {};
  const unsigned short* kb_base = kbuf + (size_t)(b * 4 + kvh) * SK * 128;
  const unsigned short* vb_base = vbuf + (size_t)(b * 4 + kvh) * SK * 128;
  for (int kt = 0; kt < SK; kt += 64) {
    __syncthreads();
    #pragma unroll
    for (int c = tid; c < 1024; c += 256) {
      int r = c >> 4, cc = (c & 15) * 8;
      *(u16x8*)&Ks[r][cc] = *(const u16x8*)&kb_base[(size_t)(kt + r) * 128 + cc];
    }
    #pragma unroll
    for (int c = tid; c < 1024; c += 256) {
      int r = c >> 4, cc = (c & 15) * 8;
      u16x8 v = *(const u16x8*)&vb_base[(size_t)(kt + r) * 128 + cc];
      #pragma unroll
      for (int j = 0; j < 8; ++j) VT[cc + j][r] = v[j];
    }
    __syncthreads();
    f32x4 sacc[4] = {};
    #pragma unroll
    for (int ks = 0; ks < 4; ++ks) {
      #pragma unroll
      for (int ni = 0; ni < 4; ++ni) {
        bf16x8 kf = *(const bf16x8*)&Ks[ni * 16 + l16][ks * 32 + kb];
        sacc[ni] = __builtin_amdgcn_mfma_f32_16x16x32_bf16(qf[ks], kf, sacc[ni], 0, 0, 0);
      }
    }
    float pv[4][4], alpha[4];
    #pragma unroll
    for (int r = 0; r < 4; ++r) {
      float tm = fmaxf(fmaxf(sacc[0][r], sacc[1][r]), fmaxf(sacc[2][r], sacc[3][r]));
      #pragma unroll
      for (int off = 1; off < 16; off <<= 1) tm = fmaxf(tm, __shfl_xor(tm, off));
      float mn = fmaxf(mrow[r], tm);
      alpha[r] = __expf(mrow[r] - mn);
      float s = 0.f;
      #pragma unroll
      for (int ni = 0; ni < 4; ++ni) {
        float p = __expf(sacc[ni][r] - mn);
        pv[ni][r] = p; s += p;
      }
      #pragma unroll
      for (int off = 1; off < 16; off <<= 1) s += __shfl_xor(s, off);
      lrow[r] = lrow[r] * alpha[r] + s;
      mrow[r] = mn;
    }
    #pragma unroll
    for (int ni = 0; ni < 8; ++ni)
      #pragma unroll
      for (int r = 0; r < 4; ++r) oacc[ni][r] *= alpha[r];
    #pragma unroll
    for (int ni = 0; ni < 4; ++ni)
      #pragma unroll
      for (int r = 0; r < 4; ++r)
        Ps[wid][r4 + r][ni * 16 + l16] = f2bf(pv[ni][r]);
    asm volatile("s_waitcnt lgkmcnt(0)" ::: "memory");
    __builtin_amdgcn_sched_barrier(0);
    #pragma unroll
    for (int ks = 0; ks < 2; ++ks) {
      bf16x8 pf = *(const bf16x8*)&Ps[wid][l16][ks * 32 + kb];
      #pragma unroll
      for (int ni = 0; ni < 8; ++ni) {
        bf16x8 vf = *(const bf16x8*)&VT[ni * 16 + l16][ks * 32 + kb];
        oacc[ni] = __builtin_amdgcn_mfma_f32_16x16x32_bf16(pf, vf, oacc[ni], 0, 0, 0);
      }
    }
  }
  #pragma unroll
  for (int ni = 0; ni < 8; ++ni)
    #pragma unroll
    for (int r = 0; r < 4; ++r) {
      float val = oacc[ni][r] / lrow[r];
      size_t row = (size_t)b * 1024 + q0 + wid * 16 + r4 + r;
      o[row * 2048 + h * 128 + ni * 16 + l16] = f2bf(val);
    }
}

// ---------------------------------------------------------------------------
// Router: one wave per token, f32 input (exact), f32 accumulate.
// ---------------------------------------------------------------------------
__global__ __launch_bounds__(64) void router_kernel(
    const float* __restrict__ xt32, const float* __restrict__ rw,
    int* __restrict__ topi, float* __restrict__ topw, int* __restrict__ counts)
{
  int t = blockIdx.x, lane = threadIdx.x;
  float acc[8] = {};
  const float* x = xt32 + (size_t)t * 2048;
  for (int d0 = lane * 4; d0 < 2048; d0 += 256) {
    float4 xv = *(const float4*)&x[d0];
    float xa[4] = {xv.x, xv.y, xv.z, xv.w};
    #pragma unroll
    for (int j = 0; j < 4; ++j) {
      const float4 r0 = *(const float4*)&rw[(d0 + j) * 8];
      const float4 r1 = *(const float4*)&rw[(d0 + j) * 8 + 4];
      acc[0] += xa[j] * r0.x; acc[1] += xa[j] * r0.y;
      acc[2] += xa[j] * r0.z; acc[3] += xa[j] * r0.w;
      acc[4] += xa[j] * r1.x; acc[5] += xa[j] * r1.y;
      acc[6] += xa[j] * r1.z; acc[7] += xa[j] * r1.w;
    }
  }
  #pragma unroll
  for (int e = 0; e < 8; ++e)
    #pragma unroll
    for (int off = 1; off < 64; off <<= 1) acc[e] += __shfl_xor(acc[e], off);
  if (lane == 0) {
    float v0 = acc[0]; int e0 = 0;
    #pragma unroll
    for (int e = 1; e < 8; ++e) if (acc[e] > v0) { v0 = acc[e]; e0 = e; }
    float v1 = -1e30f; int e1 = 0;
    #pragma unroll
    for (int e = 0; e < 8; ++e) if (e != e0 && acc[e] > v1) { v1 = acc[e]; e1 = e; }
    float x1 = expf(v1 - v0);
    float w0 = 1.f / (1.f + x1);
    float w1 = x1 / (1.f + x1);
    topi[2 * t] = e0; topi[2 * t + 1] = e1;
    topw[2 * t] = w0; topw[2 * t + 1] = w1;
    atomicAdd(&counts[e0], 1);
    atomicAdd(&counts[e1], 1);
  }
}

__global__ void scan_offsets(const int* __restrict__ counts, int* __restrict__ offsets)
{
  if (threadIdx.x == 0 && blockIdx.x == 0) {
    int a = 0;
    for (int e = 0; e < 8; ++e) { offsets[e] = a; a += counts[e]; }
    offsets[8] = a;
  }
}

__global__ __launch_bounds__(256) void scatter_pairs(
    const int* __restrict__ topi, const int* __restrict__ offsets,
    int* __restrict__ fill, int* __restrict__ pair_token, int* __restrict__ token_slot)
{
  int t = blockIdx.x * 256 + threadIdx.x;
  if (t >= 2048) return;
  #pragma unroll
  for (int k = 0; k < 2; ++k) {
    int e = topi[2 * t + k];
    int slot = offsets[e] + atomicAdd(&fill[e], 1);
    pair_token[slot] = t;
    token_slot[2 * t + k] = slot;
  }
}

__global__ __launch_bounds__(256) void act_silu(
    const float* __restrict__ gu, unsigned short* __restrict__ act)
{
  int p = blockIdx.x;
  int c = threadIdx.x * 4;
  float4 g = *(const float4*)&gu[(size_t)p * 2048 + c];
  float4 u = *(const float4*)&gu[(size_t)p * 2048 + 1024 + c];
  float gg[4] = {g.x, g.y, g.z, g.w};
  float uu[4] = {u.x, u.y, u.z, u.w};
  #pragma unroll
  for (int j = 0; j < 4; ++j) {
    float a = gg[j] / (1.f + __expf(-gg[j])) * uu[j];
    act[(size_t)p * 1024 + c + j] = f2bf(a);
  }
}

__global__ __launch_bounds__(256) void moe_combine(
    float* __restrict__ out, const float* __restrict__ eo,
    const int* __restrict__ token_slot, const float* __restrict__ topw)
{
  int t = blockIdx.x;
  int c = threadIdx.x * 8;
  int s0 = token_slot[2 * t], s1 = token_slot[2 * t + 1];
  float w0 = topw[2 * t], w1 = topw[2 * t + 1];
  #pragma unroll
  for (int j0 = 0; j0 < 8; j0 += 4) {
    float4 a = *(const float4*)&eo[(size_t)s0 * 2048 + c + j0];
    float4 b = *(const float4*)&eo[(size_t)s1 * 2048 + c + j0];
    float4 v = *(const float4*)&out[(size_t)t * 2048 + c + j0];
    v.x += w0 * a.x + w1 * b.x;
    v.y += w0 * a.y + w1 * b.y;
    v.z += w0 * a.z + w1 * b.z;
    v.w += w0 * a.w + w1 * b.w;
    *(float4*)&out[(size_t)t * 2048 + c + j0] = v;
  }
}

// ---------------------------------------------------------------------------
extern "C" void kernel_launch(void* const* d_in, const int* in_sizes, int n_in,
                              void* d_out, int out_size, void* d_ws, size_t ws_size,
                              hipStream_t stream)
{
  const float* hidden  = (const float*)d_in[0];
  const float* enc     = (const float*)d_in[1];
  const float* img_cos = (const float*)d_in[2];
  const float* img_sin = (const float*)d_in[3];
  const float* txt_cos = (const float*)d_in[4];
  const float* txt_sin = (const float*)d_in[5];
  const float* norm1_w = (const float*)d_in[6];
  const float* norm2_w = (const float*)d_in[7];
  const float* wq      = (const float*)d_in[8];
  const float* wk      = (const float*)d_in[9];
  const float* wv      = (const float*)d_in[10];
  const float* wk_txt  = (const float*)d_in[11];
  const float* wv_txt  = (const float*)d_in[12];
  const float* wo      = (const float*)d_in[13];
  const float* q_norm_w       = (const float*)d_in[14];
  const float* k_norm_w       = (const float*)d_in[15];
  const float* added_k_norm_w = (const float*)d_in[16];
  const float* router_w       = (const float*)d_in[17];
  const float* gate_up_proj   = (const float*)d_in[18];
  const float* down_proj      = (const float*)d_in[19];
  float* out = (float*)d_out;

  char* ws = (char*)d_ws;
  size_t off = 0;
  auto alloc = [&](size_t bytes) {
    void* p = ws + off;
    off += (bytes + 255) & ~(size_t)255;
    return p;
  };
  // --- bf16 transposed weights ---
  unsigned short* wqkvT  = (unsigned short*)alloc(3072ULL * 2048 * 2); // q|k|v rows
  unsigned short* wkvtT  = (unsigned short*)alloc(1024ULL * 2048 * 2); // k_txt|v_txt
  unsigned short* woT    = (unsigned short*)alloc(2048ULL * 2048 * 2);
  unsigned short* gupT   = (unsigned short*)alloc(8ULL * 2048 * 2048 * 2);
  unsigned short* dnT    = (unsigned short*)alloc(8ULL * 2048 * 1024 * 2);
  // --- activations ---
  unsigned short* x_bf   = (unsigned short*)alloc(2048ULL * 2048 * 2);
  unsigned short* enc_bf = (unsigned short*)alloc(1024ULL * 2048 * 2);
  float* qkvC = (float*)alloc(4096ULL * 2048 * 4); // [2048][3072] early; gu [4096][2048] late
  float* gu   = qkvC;                              // alias (disjoint lifetimes)
  float* kvtC = (float*)alloc(1024ULL * 1024 * 4); // [1024][1024] k_txt|v_txt
  unsigned short* qb   = (unsigned short*)alloc(2048ULL * 2048 * 2);
  unsigned short* kbuf = (unsigned short*)alloc(2ULL * 4 * 1536 * 128 * 2);
  unsigned short* vbuf = (unsigned short*)alloc(2ULL * 4 * 1536 * 128 * 2);
  unsigned short* obuf = (unsigned short*)alloc(2048ULL * 2048 * 2);
  unsigned short* act  = obuf;                     // alias (obuf dead after wo GEMM)
  unsigned short* xt   = (unsigned short*)alloc(2048ULL * 2048 * 2);
  float* xt32 = (float*)alloc(2048ULL * 2048 * 4);
  int*   ctrl  = (int*)alloc(64 * sizeof(int));    // counts[8] fill[8] offsets[9]
  int*   topi  = (int*)alloc(4096 * 4);
  float* topw  = (float*)alloc(4096 * 4);
  int*   tslot = (int*)alloc(4096 * 4);
  int*   ptok  = (int*)alloc(4096 * 4);
  unsigned short* zbuf = (unsigned short*)alloc(256);
  int* counts = ctrl, * fill = ctrl + 8, * offsets = ctrl + 16;

  hipMemsetAsync(ctrl, 0, 64, stream);
  hipMemsetAsync(zbuf, 0, 256, stream);

  const float scale = 0.08838834764831845f;  // 1/sqrt(128)

  // --- weight preprocessing: f32 [K][N] -> bf16 [N][K] ---
  convert_w<<<dim3(32, 32, 1), 256, 0, stream>>>(wq,     wqkvT,                    2048, 2048);
  convert_w<<<dim3(32,  8, 1), 256, 0, stream>>>(wk,     wqkvT + 2048ULL * 2048,   2048, 512);
  convert_w<<<dim3(32,  8, 1), 256, 0, stream>>>(wv,     wqkvT + 2560ULL * 2048,   2048, 512);
  convert_w<<<dim3(32,  8, 1), 256, 0, stream>>>(wk_txt, wkvtT,                    2048, 512);
  convert_w<<<dim3(32,  8, 1), 256, 0, stream>>>(wv_txt, wkvtT + 512ULL * 2048,    2048, 512);
  convert_w<<<dim3(32, 32, 1), 256, 0, stream>>>(wo,     woT,                      2048, 2048);
  convert_w<<<dim3(32, 32, 8), 256, 0, stream>>>(gate_up_proj, gupT,               2048, 2048);
  convert_w<<<dim3(16, 32, 8), 256, 0, stream>>>(down_proj,    dnT,                1024, 2048);

  rmsnorm_rows<<<2048, 256, 0, stream>>>(hidden, norm1_w, x_bf, nullptr);
  f32_to_bf16_k<<<2048, 256, 0, stream>>>(enc, enc_bf, 1024 * 2048);

  // fused qkv projection: [2048][2048] @ [3072][2048]^T -> [2048][3072]
  gemm_bb<<<384, 256, 0, stream>>>(x_bf, wqkvT, qkvC, nullptr, 2048, 3072, 2048);
  // fused k/v txt projection: [1024][2048] @ [1024][2048]^T -> [1024][1024]
  gemm_bb<<<64, 256, 0, stream>>>(enc_bf, wkvtT, kvtC, nullptr, 1024, 1024, 2048);

  qk_norm_rope<<<8192, 256, 0, stream>>>(qkvC, 3072, q_norm_w, img_cos, img_sin, qb,
                                         1024, 16, 1024, 0, scale);
  qk_norm_rope<<<2048, 256, 0, stream>>>(qkvC + 2048, 3072, k_norm_w, img_cos, img_sin, kbuf,
                                         1024, 4, 1536, 0, 1.0f);
  qk_norm_rope<<<1024, 256, 0, stream>>>(kvtC, 1024, added_k_norm_w, txt_cos, txt_sin, kbuf,
                                         512, 4, 1536, 1024, 1.0f);
  v_relayout<<<2048, 256, 0, stream>>>(qkvC + 2560, 3072, vbuf, 1024, 4, 1536, 0);
  v_relayout<<<1024, 256, 0, stream>>>(kvtC + 512, 1024, vbuf, 512, 4, 1536, 1024);

  attn_kernel<<<512, 256, 0, stream>>>(qb, kbuf, vbuf, obuf);

  gemm_bb<<<256, 256, 0, stream>>>(obuf, woT, out, hidden, 2048, 2048, 2048);

  rmsnorm_rows<<<2048, 256, 0, stream>>>(out, norm2_w, xt, xt32);
  router_kernel<<<2048, 64, 0, stream>>>(xt32, router_w, topi, topw, counts);
  scan_offsets<<<1, 64, 0, stream>>>(counts, offsets);
  scatter_pairs<<<8, 256, 0, stream>>>(topi, offsets, fill, ptok, tslot);

  gemm_moe_bb<<<2048, 256, 0, stream>>>(xt, gupT, gu,
                                        counts, offsets, ptok, zbuf, 1, 2048, 2048);
  act_silu<<<4096, 256, 0, stream>>>(gu, act);
  gemm_moe_bb<<<2048, 256, 0, stream>>>(act, dnT, gu,
                                        counts, offsets, ptok, zbuf, 0, 1024, 2048);
  moe_combine<<<2048, 256, 0, stream>>>(out, gu, tslot, topw);
}

// Round 8
// 632.650 us; speedup vs baseline: 1.3522x; 1.1098x over previous
//
#include <hip/hip_runtime.h>

// ---------------------------------------------------------------------------
// NucleusMoEImageTransformerBlock round 8.
// B=2 SI=1024 ST=512 D=2048 H=16 KV=4 HD=128 E=8 F=1024 TOPK=2
// Round-8 (attention only): XOR-chunk-swizzled Ks/VT/Ps LDS layouts (kills
// the 16-way V-transpose write conflict; LDS 44->40KB) + T14 async
// double-buffered register staging of K/V with raw s_barrier + lgkmcnt(0)
// (no vmcnt drain in the loop -> next tile's loads fly under compute).
// GEMMs and the rest unchanged from round 7.
// ---------------------------------------------------------------------------

typedef __attribute__((ext_vector_type(8))) __bf16 bf16x8;
typedef __attribute__((ext_vector_type(8))) unsigned short u16x8;
typedef __attribute__((ext_vector_type(4))) float f32x4;

__device__ __forceinline__ unsigned short f2bf(float x) {
  unsigned u = __builtin_bit_cast(unsigned, x);
  u += 0x7fffu + ((u >> 16) & 1u);        // RNE
  return (unsigned short)(u >> 16);
}
__device__ __forceinline__ float bf2f(unsigned short b) {
  return __builtin_bit_cast(float, ((unsigned)b) << 16);
}

__device__ __forceinline__ void glds16(const unsigned short* g, unsigned short* l) {
  __builtin_amdgcn_global_load_lds(
      (const __attribute__((address_space(1))) void*)g,
      (__attribute__((address_space(3))) void*)l, 16, 0, 0);
}

// m204 bijective XCD chunk swizzle.
__device__ __forceinline__ int xcd_swz(int orig, int nwg) {
  int q = nwg >> 3, r = nwg & 7;
  int xcd = orig & 7, idx = orig >> 3;
  int base = (xcd < r) ? xcd * (q + 1) : r * (q + 1) + (xcd - r) * q;
  return base + idx;
}

// ---------------------------------------------------------------------------
// Weight convert+transpose: W f32 [K][N] -> WT bf16 [N][K].
// ---------------------------------------------------------------------------
__global__ __launch_bounds__(256) void convert_w(
    const float* __restrict__ W, unsigned short* __restrict__ WT,
    int K, int N)
{
  __shared__ unsigned short T[64][66];
  const float* Wz = W + (size_t)blockIdx.z * K * N;
  unsigned short* WTz = WT + (size_t)blockIdx.z * K * N;
  const int k0 = blockIdx.x * 64, n0 = blockIdx.y * 64;
  const int tid = threadIdx.x;
  #pragma unroll
  for (int i = tid; i < 64 * 16; i += 256) {
    int k = i >> 4, n4 = (i & 15) * 4;
    float4 v = *(const float4*)&Wz[(size_t)(k0 + k) * N + n0 + n4];
    T[n4 + 0][k] = f2bf(v.x);
    T[n4 + 1][k] = f2bf(v.y);
    T[n4 + 2][k] = f2bf(v.z);
    T[n4 + 3][k] = f2bf(v.w);
  }
  __syncthreads();
  #pragma unroll
  for (int i = tid; i < 64 * 8; i += 256) {
    int n = i >> 3, k8 = (i & 7) * 8;
    *(u16x8*)&WTz[(size_t)(n0 + n) * K + k0 + k8] = *(const u16x8*)&T[n][k8];
  }
}

// ---------------------------------------------------------------------------
// Dense GEMM: C[M,N] = A[M,K] @ BT[N,K]^T (+resid). bf16 in, f32 out.
// ---------------------------------------------------------------------------
__global__ __launch_bounds__(256) void gemm_bb(
    const unsigned short* __restrict__ A, const unsigned short* __restrict__ BT,
    float* __restrict__ C, const float* __restrict__ resid,
    int M, int N, int K)
{
  __shared__ unsigned short As[2][128 * 64];
  __shared__ unsigned short Bs[2][128 * 64];
  const int mb = M >> 7;
  const int w = xcd_swz(blockIdx.x, gridDim.x);
  const int bm = (w % mb) * 128, bn = (w / mb) * 128;
  const int tid = threadIdx.x, lane = tid & 63, wid = tid >> 6;
  const int wm = (wid >> 1) * 64, wn = (wid & 1) * 64;
  const int l16 = lane & 15, g4 = lane >> 4;
  const int rseg = lane >> 3;
  const int csw  = ((lane & 7) ^ rseg) * 8;
  const unsigned short* aSrc[4];
  const unsigned short* bSrc[4];
  #pragma unroll
  for (int p = 0; p < 4; ++p) {
    int row = (p * 4 + wid) * 8 + rseg;
    aSrc[p] = A  + (size_t)(bm + row) * K + csw;
    bSrc[p] = BT + (size_t)(bn + row) * K + csw;
  }
  f32x4 acc[4][4] = {};
  const int NT = K >> 6;
  #pragma unroll
  for (int p = 0; p < 4; ++p) glds16(aSrc[p], &As[0][(p * 4 + wid) * 512]);
  #pragma unroll
  for (int p = 0; p < 4; ++p) glds16(bSrc[p], &Bs[0][(p * 4 + wid) * 512]);
  for (int t = 0; t < NT; ++t) {
    const int cur = t & 1;
    if (t + 1 < NT) {
      const int k0 = (t + 1) << 6;
      #pragma unroll
      for (int p = 0; p < 4; ++p) glds16(aSrc[p] + k0, &As[cur ^ 1][(p * 4 + wid) * 512]);
      #pragma unroll
      for (int p = 0; p < 4; ++p) glds16(bSrc[p] + k0, &Bs[cur ^ 1][(p * 4 + wid) * 512]);
      asm volatile("s_waitcnt vmcnt(8)" ::: "memory");
    } else {
      asm volatile("s_waitcnt vmcnt(0)" ::: "memory");
    }
    __builtin_amdgcn_s_barrier();
    __builtin_amdgcn_sched_barrier(0);
    const unsigned short* ab = &As[cur][0];
    const unsigned short* bb = &Bs[cur][0];
    #pragma unroll
    for (int ks = 0; ks < 2; ++ks) {
      bf16x8 af[4], bf[4];
      #pragma unroll
      for (int i = 0; i < 4; ++i) {
        int ra = wm + i * 16 + l16;
        int rb = wn + i * 16 + l16;
        int ch = ((ks * 4 + g4) ^ (l16 & 7)) * 8;
        af[i] = *(const bf16x8*)&ab[ra * 64 + ch];
        bf[i] = *(const bf16x8*)&bb[rb * 64 + ch];
      }
      #pragma unroll
      for (int mi = 0; mi < 4; ++mi)
        #pragma unroll
        for (int ni = 0; ni < 4; ++ni)
          acc[mi][ni] = __builtin_amdgcn_mfma_f32_16x16x32_bf16(af[mi], bf[ni], acc[mi][ni], 0, 0, 0);
    }
    __builtin_amdgcn_sched_barrier(0);
    __builtin_amdgcn_s_barrier();
  }
  const int r4 = g4 * 4;
  #pragma unroll
  for (int mi = 0; mi < 4; ++mi)
    #pragma unroll
    for (int ni = 0; ni < 4; ++ni)
      #pragma unroll
      for (int r = 0; r < 4; ++r) {
        int row = bm + wm + mi * 16 + r4 + r;
        int col = bn + wn + ni * 16 + l16;
        float v = acc[mi][ni][r];
        if (resid) v += resid[(size_t)row * N + col];
        C[(size_t)row * N + col] = v;
      }
}

// ---------------------------------------------------------------------------
// Expert-batched MoE GEMM. 1D grid 2048, XCD-swizzled (one expert per XCD).
// ---------------------------------------------------------------------------
__global__ __launch_bounds__(256) void gemm_moe_bb(
    const unsigned short* __restrict__ A, const unsigned short* __restrict__ BTall,
    float* __restrict__ C,
    const int* __restrict__ counts, const int* __restrict__ offsets,
    const int* __restrict__ pair_token, const unsigned short* __restrict__ zbuf,
    int gather, int K, int N)
{
  const int w = xcd_swz(blockIdx.x, gridDim.x);
  const int e = w >> 8;
  const int cnt = counts[e];
  const int bm = (w & 15) * 128;
  if (bm >= cnt) return;
  const int base = offsets[e];
  const int bn = ((w >> 4) & 15) * 128;
  __shared__ unsigned short As[2][128 * 64];
  __shared__ unsigned short Bs[2][128 * 64];
  const int tid = threadIdx.x, lane = tid & 63, wid = tid >> 6;
  const int wm = (wid >> 1) * 64, wn = (wid & 1) * 64;
  const int l16 = lane & 15, g4 = lane >> 4;
  const int rseg = lane >> 3;
  const int csw  = ((lane & 7) ^ rseg) * 8;
  const unsigned short* BT = BTall + (size_t)e * N * K;
  const unsigned short* aSrc[4];
  const unsigned short* bSrc[4];
  int aOk[4];
  #pragma unroll
  for (int p = 0; p < 4; ++p) {
    int row = (p * 4 + wid) * 8 + rseg;
    int lr = bm + row;
    int tok = -1;
    if (lr < cnt) tok = gather ? pair_token[base + lr] : base + lr;
    aOk[p] = (tok >= 0);
    aSrc[p] = aOk[p] ? (A + (size_t)tok * K + csw) : (zbuf + csw);
    bSrc[p] = BT + (size_t)(bn + row) * K + csw;
  }
  f32x4 acc[4][4] = {};
  const int NT = K >> 6;
  #pragma unroll
  for (int p = 0; p < 4; ++p) glds16(aSrc[p], &As[0][(p * 4 + wid) * 512]);
  #pragma unroll
  for (int p = 0; p < 4; ++p) glds16(bSrc[p], &Bs[0][(p * 4 + wid) * 512]);
  for (int t = 0; t < NT; ++t) {
    const int cur = t & 1;
    if (t + 1 < NT) {
      const int k0 = (t + 1) << 6;
      #pragma unroll
      for (int p = 0; p < 4; ++p)
        glds16(aSrc[p] + (aOk[p] ? k0 : 0), &As[cur ^ 1][(p * 4 + wid) * 512]);
      #pragma unroll
      for (int p = 0; p < 4; ++p)
        glds16(bSrc[p] + k0, &Bs[cur ^ 1][(p * 4 + wid) * 512]);
      asm volatile("s_waitcnt vmcnt(8)" ::: "memory");
    } else {
      asm volatile("s_waitcnt vmcnt(0)" ::: "memory");
    }
    __builtin_amdgcn_s_barrier();
    __builtin_amdgcn_sched_barrier(0);
    const unsigned short* ab = &As[cur][0];
    const unsigned short* bb = &Bs[cur][0];
    #pragma unroll
    for (int ks = 0; ks < 2; ++ks) {
      bf16x8 af[4], bf[4];
      #pragma unroll
      for (int i = 0; i < 4; ++i) {
        int ra = wm + i * 16 + l16;
        int rb = wn + i * 16 + l16;
        int ch = ((ks * 4 + g4) ^ (l16 & 7)) * 8;
        af[i] = *(const bf16x8*)&ab[ra * 64 + ch];
        bf[i] = *(const bf16x8*)&bb[rb * 64 + ch];
      }
      #pragma unroll
      for (int mi = 0; mi < 4; ++mi)
        #pragma unroll
        for (int ni = 0; ni < 4; ++ni)
          acc[mi][ni] = __builtin_amdgcn_mfma_f32_16x16x32_bf16(af[mi], bf[ni], acc[mi][ni], 0, 0, 0);
    }
    __builtin_amdgcn_sched_barrier(0);
    __builtin_amdgcn_s_barrier();
  }
  const int r4 = g4 * 4;
  #pragma unroll
  for (int mi = 0; mi < 4; ++mi)
    #pragma unroll
    for (int ni = 0; ni < 4; ++ni)
      #pragma unroll
      for (int r = 0; r < 4; ++r) {
        int lrow = bm + wm + mi * 16 + r4 + r;
        int col  = bn + wn + ni * 16 + l16;
        if (lrow < cnt)
          C[(size_t)(base + lrow) * N + col] = acc[mi][ni][r];
      }
}

// ---------------------------------------------------------------------------
// RMSNorm over D=2048, f32 in -> bf16 out (+ optional exact f32 out).
// ---------------------------------------------------------------------------
__global__ __launch_bounds__(256) void rmsnorm_rows(
    const float* __restrict__ in, const float* __restrict__ w,
    unsigned short* __restrict__ out, float* __restrict__ out32)
{
  const int row = blockIdx.x;
  const int tid = threadIdx.x;
  const float* x = in + (size_t)row * 2048;
  float4 a = *(const float4*)&x[tid * 8];
  float4 b = *(const float4*)&x[tid * 8 + 4];
  float s = a.x*a.x + a.y*a.y + a.z*a.z + a.w*a.w
          + b.x*b.x + b.y*b.y + b.z*b.z + b.w*b.w;
  #pragma unroll
  for (int off = 1; off < 64; off <<= 1) s += __shfl_xor(s, off);
  __shared__ float red[4];
  if ((tid & 63) == 0) red[tid >> 6] = s;
  __syncthreads();
  float inv = rsqrtf((red[0] + red[1] + red[2] + red[3]) * (1.f / 2048.f) + 1e-6f);
  float4 wa = *(const float4*)&w[tid * 8];
  float4 wb = *(const float4*)&w[tid * 8 + 4];
  float y[8] = {a.x * inv * wa.x, a.y * inv * wa.y, a.z * inv * wa.z, a.w * inv * wa.w,
                b.x * inv * wb.x, b.y * inv * wb.y, b.z * inv * wb.z, b.w * inv * wb.w};
  unsigned short* o = out + (size_t)row * 2048 + tid * 8;
  #pragma unroll
  for (int j = 0; j < 8; ++j) o[j] = f2bf(y[j]);
  if (out32) {
    float* o32 = out32 + (size_t)row * 2048 + tid * 8;
    *(float4*)&o32[0] = make_float4(y[0], y[1], y[2], y[3]);
    *(float4*)&o32[4] = make_float4(y[4], y[5], y[6], y[7]);
  }
}

__global__ __launch_bounds__(256) void f32_to_bf16_k(
    const float* __restrict__ in, unsigned short* __restrict__ out, int n)
{
  int i = (blockIdx.x * 256 + threadIdx.x) * 4;
  if (i + 3 < n) {
    float4 v = *(const float4*)&in[i];
    out[i + 0] = f2bf(v.x); out[i + 1] = f2bf(v.y);
    out[i + 2] = f2bf(v.z); out[i + 3] = f2bf(v.w);
  }
}

// ---------------------------------------------------------------------------
// Per-(b,s,h) head RMSNorm + RoPE, relayout to (B, NH, seq_total, 128) bf16.
// ---------------------------------------------------------------------------
__global__ __launch_bounds__(256) void qk_norm_rope(
    const float* __restrict__ raw, int ld, const float* __restrict__ nw,
    const float* __restrict__ cosT, const float* __restrict__ sinT,
    unsigned short* __restrict__ out,
    int S, int NH, int seq_total, int s_off, float premul)
{
  int rowid = blockIdx.x * 4 + (threadIdx.x >> 6);
  int lane  = threadIdx.x & 63;
  int b = rowid / (S * NH);
  int rem = rowid % (S * NH);
  int s = rem / NH, h = rem % NH;
  const float* src = raw + (size_t)(b * S + s) * ld + h * 128;
  float2 xv = *(const float2*)&src[lane * 2];
  float ss = xv.x * xv.x + xv.y * xv.y;
  #pragma unroll
  for (int off = 1; off < 64; off <<= 1) ss += __shfl_xor(ss, off);
  float inv = rsqrtf(ss * (1.f / 128.f) + 1e-6f);
  float yr = xv.x * inv * nw[lane * 2];
  float yi = xv.y * inv * nw[lane * 2 + 1];
  float c  = cosT[s * 64 + lane], sn = sinT[s * 64 + lane];
  float orr = (yr * c - yi * sn) * premul;
  float oi  = (yr * sn + yi * c) * premul;
  unsigned short* dst = out + ((size_t)(b * NH + h) * seq_total + (s + s_off)) * 128;
  dst[lane * 2]     = f2bf(orr);
  dst[lane * 2 + 1] = f2bf(oi);
}

__global__ __launch_bounds__(256) void v_relayout(
    const float* __restrict__ raw, int ld, unsigned short* __restrict__ out,
    int S, int NH, int seq_total, int s_off)
{
  int rowid = blockIdx.x * 4 + (threadIdx.x >> 6);
  int lane  = threadIdx.x & 63;
  int b = rowid / (S * NH);
  int rem = rowid % (S * NH);
  int s = rem / NH, h = rem % NH;
  const float* src = raw + (size_t)(b * S + s) * ld + h * 128;
  float2 xv = *(const float2*)&src[lane * 2];
  unsigned short* dst = out + ((size_t)(b * NH + h) * seq_total + (s + s_off)) * 128;
  dst[lane * 2]     = f2bf(xv.x);
  dst[lane * 2 + 1] = f2bf(xv.y);
}

// ---------------------------------------------------------------------------
// Flash attention: 64 q-rows/block (4 waves x 16 rows), Sk tiles of 64.
// XOR-swizzled LDS (Ks[64][128], VT[128][64], Ps[4][16][64], all linear
// stride + chunk^row XOR -> no >2-way conflicts) + async dbuf reg staging.
// ---------------------------------------------------------------------------
__global__ __launch_bounds__(256) void attn_kernel(
    const unsigned short* __restrict__ q,    // (B,16,1024,128)
    const unsigned short* __restrict__ kbuf, // (B,4,1536,128)
    const unsigned short* __restrict__ vbuf, // (B,4,1536,128)
    unsigned short* __restrict__ o)          // (B*1024, 2048)
{
  const int SK = 1536;
  const int w = xcd_swz(blockIdx.x, gridDim.x);
  const int bh = w >> 4;
  const int b = bh >> 4, h = bh & 15, kvh = h >> 2;
  const int q0 = (w & 15) * 64;
  const int tid = threadIdx.x, lane = tid & 63, wid = tid >> 6;
  const int l16 = lane & 15, kb = (lane >> 4) * 8, r4 = (lane >> 4) * 4;
  __shared__ unsigned short KsL[64 * 128];   // [kv][d], chunk^(kv&7) swizzle
  __shared__ unsigned short VTL[128 * 64];   // [d][kv], chunk^((d>>3)&7) swizzle
  __shared__ unsigned short PsL[4 * 16 * 64];// per-wave [row][col], chunk^(row&7)
  const int sr0 = tid >> 4;          // staging kv row base (0..15)
  const int scc = (tid & 15) * 8;    // staging d col (0..120)

  const unsigned short* qrow =
      q + ((size_t)(b * 16 + h) * 1024 + q0 + wid * 16 + l16) * 128;
  bf16x8 qf[4];
  #pragma unroll
  for (int ks = 0; ks < 4; ++ks) qf[ks] = *(const bf16x8*)&qrow[ks * 32 + kb];
  float mrow[4] = {-1e30f, -1e30f, -1e30f, -1e30f};
  float lrow[4] = {0.f, 0.f, 0.f, 0.f};
  f32x4 oacc[8] = {};
  const unsigned short* kb_base = kbuf + (size_t)(b * 4 + kvh) * SK * 128;
  const unsigned short* vb_base = vbuf + (size_t)(b * 4 + kvh) * SK * 128;

  u16x8 k0[4], v0[4], k1[4], v1[4];

#define ATT_LOAD(kr, vr, kt1)                                                 \
  {                                                                           \
    _Pragma("unroll")                                                         \
    for (int i = 0; i < 4; ++i) {                                             \
      kr[i] = *(const u16x8*)&kb_base[(size_t)((kt1) + sr0 + 16 * i) * 128 + scc]; \
      vr[i] = *(const u16x8*)&vb_base[(size_t)((kt1) + sr0 + 16 * i) * 128 + scc]; \
    }                                                                         \
  }

#define ATT_STAGE(kr, vr)                                                     \
  {                                                                           \
    _Pragma("unroll")                                                         \
    for (int i = 0; i < 4; ++i) {                                             \
      int rr = sr0 + 16 * i;                                                  \
      *(u16x8*)&KsL[rr * 128 + (((scc >> 3) ^ (rr & 7)) << 3)] = kr[i];       \
      _Pragma("unroll")                                                       \
      for (int j = 0; j < 8; ++j)                                             \
        VTL[(scc + j) * 64 + ((((rr >> 3) ^ ((scc + j) >> 3)) & 7) << 3) + (rr & 7)] = vr[i][j]; \
    }                                                                         \
  }

  auto compute = [&]() {
    f32x4 sacc[4] = {};
    #pragma unroll
    for (int ks = 0; ks < 4; ++ks) {
      #pragma unroll
      for (int ni = 0; ni < 4; ++ni) {
        int rr = ni * 16 + l16;
        bf16x8 kf = *(const bf16x8*)
            &KsL[rr * 128 + ((((ks * 32 + kb) >> 3) ^ (rr & 7)) << 3)];
        sacc[ni] = __builtin_amdgcn_mfma_f32_16x16x32_bf16(qf[ks], kf, sacc[ni], 0, 0, 0);
      }
    }
    float pv[4][4], alpha[4];
    #pragma unroll
    for (int r = 0; r < 4; ++r) {
      float tm = fmaxf(fmaxf(sacc[0][r], sacc[1][r]), fmaxf(sacc[2][r], sacc[3][r]));
      #pragma unroll
      for (int off = 1; off < 16; off <<= 1) tm = fmaxf(tm, __shfl_xor(tm, off));
      float mn = fmaxf(mrow[r], tm);
      alpha[r] = __expf(mrow[r] - mn);
      float s = 0.f;
      #pragma unroll
      for (int ni = 0; ni < 4; ++ni) {
        float p = __expf(sacc[ni][r] - mn);
        pv[ni][r] = p; s += p;
      }
      #pragma unroll
      for (int off = 1; off < 16; off <<= 1) s += __shfl_xor(s, off);
      lrow[r] = lrow[r] * alpha[r] + s;
      mrow[r] = mn;
    }
    #pragma unroll
    for (int ni = 0; ni < 8; ++ni)
      #pragma unroll
      for (int r = 0; r < 4; ++r) oacc[ni][r] *= alpha[r];
    #pragma unroll
    for (int ni = 0; ni < 4; ++ni)
      #pragma unroll
      for (int r = 0; r < 4; ++r) {
        int row = r4 + r, col = ni * 16 + l16;
        PsL[wid * 1024 + row * 64 + ((((col >> 3) ^ (row & 7)) & 7) << 3) + (col & 7)]
            = f2bf(pv[ni][r]);
      }
    asm volatile("s_waitcnt lgkmcnt(0)" ::: "memory");
    __builtin_amdgcn_sched_barrier(0);
    #pragma unroll
    for (int ks = 0; ks < 2; ++ks) {
      bf16x8 pf = *(const bf16x8*)
          &PsL[wid * 1024 + l16 * 64 + ((((ks * 32 + kb) >> 3) ^ (l16 & 7)) << 3)];
      #pragma unroll
      for (int ni = 0; ni < 8; ++ni) {
        int d = ni * 16 + l16;
        bf16x8 vf = *(const bf16x8*)
            &VTL[d * 64 + ((((ks * 32 + kb) >> 3) ^ ((d >> 3) & 7)) << 3)];
        oacc[ni] = __builtin_amdgcn_mfma_f32_16x16x32_bf16(pf, vf, oacc[ni], 0, 0, 0);
      }
    }
  };

  ATT_LOAD(k0, v0, 0);
  for (int t = 0; t < 24; t += 2) {
    ATT_STAGE(k0, v0);
    ATT_LOAD(k1, v1, (t + 1) * 64);
    asm volatile("s_waitcnt lgkmcnt(0)" ::: "memory");
    __builtin_amdgcn_s_barrier();
    __builtin_amdgcn_sched_barrier(0);
    compute();
    __builtin_amdgcn_sched_barrier(0);
    __builtin_amdgcn_s_barrier();
    ATT_STAGE(k1, v1);
    if (t + 2 < 24) ATT_LOAD(k0, v0, (t + 2) * 64);
    asm volatile("s_waitcnt lgkmcnt(0)" ::: "memory");
    __builtin_amdgcn_s_barrier();
    __builtin_amdgcn_sched_barrier(0);
    compute();
    __builtin_amdgcn_sched_barrier(0);
    __builtin_amdgcn_s_barrier();
  }
#undef ATT_LOAD
#undef ATT_STAGE

  #pragma unroll
  for (int ni = 0; ni < 8; ++ni)
    #pragma unroll
    for (int r = 0; r < 4; ++r) {
      float val = oacc[ni][r] / lrow[r];
      size_t row = (size_t)b * 1024 + q0 + wid * 16 + r4 + r;
      o[row * 2048 + h * 128 + ni * 16 + l16] = f2bf(val);
    }
}

// ---------------------------------------------------------------------------
// Router: one wave per token, f32 input (exact), f32 accumulate.
// ---------------------------------------------------------------------------
__global__ __launch_bounds__(64) void router_kernel(
    const float* __restrict__ xt32, const float* __restrict__ rw,
    int* __restrict__ topi, float* __restrict__ topw, int* __restrict__ counts)
{
  int t = blockIdx.x, lane = threadIdx.x;
  float acc[8] = {};
  const float* x = xt32 + (size_t)t * 2048;
  for (int d0 = lane * 4; d0 < 2048; d0 += 256) {
    float4 xv = *(const float4*)&x[d0];
    float xa[4] = {xv.x, xv.y, xv.z, xv.w};
    #pragma unroll
    for (int j = 0; j < 4; ++j) {
      const float4 r0 = *(const float4*)&rw[(d0 + j) * 8];
      const float4 r1 = *(const float4*)&rw[(d0 + j) * 8 + 4];
      acc[0] += xa[j] * r0.x; acc[1] += xa[j] * r0.y;
      acc[2] += xa[j] * r0.z; acc[3] += xa[j] * r0.w;
      acc[4] += xa[j] * r1.x; acc[5] += xa[j] * r1.y;
      acc[6] += xa[j] * r1.z; acc[7] += xa[j] * r1.w;
    }
  }
  #pragma unroll
  for (int e = 0; e < 8; ++e)
    #pragma unroll
    for (int off = 1; off < 64; off <<= 1) acc[e] += __shfl_xor(acc[e], off);
  if (lane == 0) {
    float v0 = acc[0]; int e0 = 0;
    #pragma unroll
    for (int e = 1; e < 8; ++e) if (acc[e] > v0) { v0 = acc[e]; e0 = e; }
    float v1 = -1e30f; int e1 = 0;
    #pragma unroll
    for (int e = 0; e < 8; ++e) if (e != e0 && acc[e] > v1) { v1 = acc[e]; e1 = e; }
    float x1 = expf(v1 - v0);
    float w0 = 1.f / (1.f + x1);
    float w1 = x1 / (1.f + x1);
    topi[2 * t] = e0; topi[2 * t + 1] = e1;
    topw[2 * t] = w0; topw[2 * t + 1] = w1;
    atomicAdd(&counts[e0], 1);
    atomicAdd(&counts[e1], 1);
  }
}

__global__ void scan_offsets(const int* __restrict__ counts, int* __restrict__ offsets)
{
  if (threadIdx.x == 0 && blockIdx.x == 0) {
    int a = 0;
    for (int e = 0; e < 8; ++e) { offsets[e] = a; a += counts[e]; }
    offsets[8] = a;
  }
}

__global__ __launch_bounds__(256) void scatter_pairs(
    const int* __restrict__ topi, const int* __restrict__ offsets,
    int* __restrict__ fill, int* __restrict__ pair_token, int* __restrict__ token_slot)
{
  int t = blockIdx.x * 256 + threadIdx.x;
  if (t >= 2048) return;
  #pragma unroll
  for (int k = 0; k < 2; ++k) {
    int e = topi[2 * t + k];
    int slot = offsets[e] + atomicAdd(&fill[e], 1);
    pair_token[slot] = t;
    token_slot[2 * t + k] = slot;
  }
}

__global__ __launch_bounds__(256) void act_silu(
    const float* __restrict__ gu, unsigned short* __restrict__ act)
{
  int p = blockIdx.x;
  int c = threadIdx.x * 4;
  float4 g = *(const float4*)&gu[(size_t)p * 2048 + c];
  float4 u = *(const float4*)&gu[(size_t)p * 2048 + 1024 + c];
  float gg[4] = {g.x, g.y, g.z, g.w};
  float uu[4] = {u.x, u.y, u.z, u.w};
  #pragma unroll
  for (int j = 0; j < 4; ++j) {
    float a = gg[j] / (1.f + __expf(-gg[j])) * uu[j];
    act[(size_t)p * 1024 + c + j] = f2bf(a);
  }
}

__global__ __launch_bounds__(256) void moe_combine(
    float* __restrict__ out, const float* __restrict__ eo,
    const int* __restrict__ token_slot, const float* __restrict__ topw)
{
  int t = blockIdx.x;
  int c = threadIdx.x * 8;
  int s0 = token_slot[2 * t], s1 = token_slot[2 * t + 1];
  float w0 = topw[2 * t], w1 = topw[2 * t + 1];
  #pragma unroll
  for (int j0 = 0; j0 < 8; j0 += 4) {
    float4 a = *(const float4*)&eo[(size_t)s0 * 2048 + c + j0];
    float4 b = *(const float4*)&eo[(size_t)s1 * 2048 + c + j0];
    float4 v = *(const float4*)&out[(size_t)t * 2048 + c + j0];
    v.x += w0 * a.x + w1 * b.x;
    v.y += w0 * a.y + w1 * b.y;
    v.z += w0 * a.z + w1 * b.z;
    v.w += w0 * a.w + w1 * b.w;
    *(float4*)&out[(size_t)t * 2048 + c + j0] = v;
  }
}

// ---------------------------------------------------------------------------
extern "C" void kernel_launch(void* const* d_in, const int* in_sizes, int n_in,
                              void* d_out, int out_size, void* d_ws, size_t ws_size,
                              hipStream_t stream)
{
  const float* hidden  = (const float*)d_in[0];
  const float* enc     = (const float*)d_in[1];
  const float* img_cos = (const float*)d_in[2];
  const float* img_sin = (const float*)d_in[3];
  const float* txt_cos = (const float*)d_in[4];
  const float* txt_sin = (const float*)d_in[5];
  const float* norm1_w = (const float*)d_in[6];
  const float* norm2_w = (const float*)d_in[7];
  const float* wq      = (const float*)d_in[8];
  const float* wk      = (const float*)d_in[9];
  const float* wv      = (const float*)d_in[10];
  const float* wk_txt  = (const float*)d_in[11];
  const float* wv_txt  = (const float*)d_in[12];
  const float* wo      = (const float*)d_in[13];
  const float* q_norm_w       = (const float*)d_in[14];
  const float* k_norm_w       = (const float*)d_in[15];
  const float* added_k_norm_w = (const float*)d_in[16];
  const float* router_w       = (const float*)d_in[17];
  const float* gate_up_proj   = (const float*)d_in[18];
  const float* down_proj      = (const float*)d_in[19];
  float* out = (float*)d_out;

  char* ws = (char*)d_ws;
  size_t off = 0;
  auto alloc = [&](size_t bytes) {
    void* p = ws + off;
    off += (bytes + 255) & ~(size_t)255;
    return p;
  };
  // --- bf16 transposed weights ---
  unsigned short* wqkvT  = (unsigned short*)alloc(3072ULL * 2048 * 2); // q|k|v rows
  unsigned short* wkvtT  = (unsigned short*)alloc(1024ULL * 2048 * 2); // k_txt|v_txt
  unsigned short* woT    = (unsigned short*)alloc(2048ULL * 2048 * 2);
  unsigned short* gupT   = (unsigned short*)alloc(8ULL * 2048 * 2048 * 2);
  unsigned short* dnT    = (unsigned short*)alloc(8ULL * 2048 * 1024 * 2);
  // --- activations ---
  unsigned short* x_bf   = (unsigned short*)alloc(2048ULL * 2048 * 2);
  unsigned short* enc_bf = (unsigned short*)alloc(1024ULL * 2048 * 2);
  float* qkvC = (float*)alloc(4096ULL * 2048 * 4); // [2048][3072] early; gu [4096][2048] late
  float* gu   = qkvC;                              // alias (disjoint lifetimes)
  float* kvtC = (float*)alloc(1024ULL * 1024 * 4); // [1024][1024] k_txt|v_txt
  unsigned short* qb   = (unsigned short*)alloc(2048ULL * 2048 * 2);
  unsigned short* kbuf = (unsigned short*)alloc(2ULL * 4 * 1536 * 128 * 2);
  unsigned short* vbuf = (unsigned short*)alloc(2ULL * 4 * 1536 * 128 * 2);
  unsigned short* obuf = (unsigned short*)alloc(2048ULL * 2048 * 2);
  unsigned short* act  = obuf;                     // alias (obuf dead after wo GEMM)
  unsigned short* xt   = (unsigned short*)alloc(2048ULL * 2048 * 2);
  float* xt32 = (float*)alloc(2048ULL * 2048 * 4);
  int*   ctrl  = (int*)alloc(64 * sizeof(int));    // counts[8] fill[8] offsets[9]
  int*   topi  = (int*)alloc(4096 * 4);
  float* topw  = (float*)alloc(4096 * 4);
  int*   tslot = (int*)alloc(4096 * 4);
  int*   ptok  = (int*)alloc(4096 * 4);
  unsigned short* zbuf = (unsigned short*)alloc(256);
  int* counts = ctrl, * fill = ctrl + 8, * offsets = ctrl + 16;

  hipMemsetAsync(ctrl, 0, 64, stream);
  hipMemsetAsync(zbuf, 0, 256, stream);

  const float scale = 0.08838834764831845f;  // 1/sqrt(128)

  // --- weight preprocessing: f32 [K][N] -> bf16 [N][K] ---
  convert_w<<<dim3(32, 32, 1), 256, 0, stream>>>(wq,     wqkvT,                    2048, 2048);
  convert_w<<<dim3(32,  8, 1), 256, 0, stream>>>(wk,     wqkvT + 2048ULL * 2048,   2048, 512);
  convert_w<<<dim3(32,  8, 1), 256, 0, stream>>>(wv,     wqkvT + 2560ULL * 2048,   2048, 512);
  convert_w<<<dim3(32,  8, 1), 256, 0, stream>>>(wk_txt, wkvtT,                    2048, 512);
  convert_w<<<dim3(32,  8, 1), 256, 0, stream>>>(wv_txt, wkvtT + 512ULL * 2048,    2048, 512);
  convert_w<<<dim3(32, 32, 1), 256, 0, stream>>>(wo,     woT,                      2048, 2048);
  convert_w<<<dim3(32, 32, 8), 256, 0, stream>>>(gate_up_proj, gupT,               2048, 2048);
  convert_w<<<dim3(16, 32, 8), 256, 0, stream>>>(down_proj,    dnT,                1024, 2048);

  rmsnorm_rows<<<2048, 256, 0, stream>>>(hidden, norm1_w, x_bf, nullptr);
  f32_to_bf16_k<<<2048, 256, 0, stream>>>(enc, enc_bf, 1024 * 2048);

  // fused qkv projection: [2048][2048] @ [3072][2048]^T -> [2048][3072]
  gemm_bb<<<384, 256, 0, stream>>>(x_bf, wqkvT, qkvC, nullptr, 2048, 3072, 2048);
  // fused k/v txt projection: [1024][2048] @ [1024][2048]^T -> [1024][1024]
  gemm_bb<<<64, 256, 0, stream>>>(enc_bf, wkvtT, kvtC, nullptr, 1024, 1024, 2048);

  qk_norm_rope<<<8192, 256, 0, stream>>>(qkvC, 3072, q_norm_w, img_cos, img_sin, qb,
                                         1024, 16, 1024, 0, scale);
  qk_norm_rope<<<2048, 256, 0, stream>>>(qkvC + 2048, 3072, k_norm_w, img_cos, img_sin, kbuf,
                                         1024, 4, 1536, 0, 1.0f);
  qk_norm_rope<<<1024, 256, 0, stream>>>(kvtC, 1024, added_k_norm_w, txt_cos, txt_sin, kbuf,
                                         512, 4, 1536, 1024, 1.0f);
  v_relayout<<<2048, 256, 0, stream>>>(qkvC + 2560, 3072, vbuf, 1024, 4, 1536, 0);
  v_relayout<<<1024, 256, 0, stream>>>(kvtC + 512, 1024, vbuf, 512, 4, 1536, 1024);

  attn_kernel<<<512, 256, 0, stream>>>(qb, kbuf, vbuf, obuf);

  gemm_bb<<<256, 256, 0, stream>>>(obuf, woT, out, hidden, 2048, 2048, 2048);

  rmsnorm_rows<<<2048, 256, 0, stream>>>(out, norm2_w, xt, xt32);
  router_kernel<<<2048, 64, 0, stream>>>(xt32, router_w, topi, topw, counts);
  scan_offsets<<<1, 64, 0, stream>>>(counts, offsets);
  scatter_pairs<<<8, 256, 0, stream>>>(topi, offsets, fill, ptok, tslot);

  gemm_moe_bb<<<2048, 256, 0, stream>>>(xt, gupT, gu,
                                        counts, offsets, ptok, zbuf, 1, 2048, 2048);
  act_silu<<<4096, 256, 0, stream>>>(gu, act);
  gemm_moe_bb<<<2048, 256, 0, stream>>>(act, dnT, gu,
                                        counts, offsets, ptok, zbuf, 0, 1024, 2048);
  moe_combine<<<2048, 256, 0, stream>>>(out, gu, tslot, topw);
}

// Round 9
// 630.329 us; speedup vs baseline: 1.3572x; 1.0037x over previous
//
#include <hip/hip_runtime.h>

// ---------------------------------------------------------------------------
// NucleusMoEImageTransformerBlock round 9.
// B=2 SI=1024 ST=512 D=2048 H=16 KV=4 HD=128 E=8 F=1024 TOPK=2
// Round-9: MoE GEMM -> 256x256 tile, 512 threads (8 waves 2x4), BK=64,
// single-buffer 64KB LDS, XOR chunk swizzle. Halves LDS-staging traffic
// (A x8 + B x2 = 256MB vs 512MB) -- r8 analysis showed the MoE GEMM is
// bound by aggregate L2/L3/HBM serving rate (~5.2 TB/s), not schedule.
// Dense GEMMs / attention unchanged from r8.
// ---------------------------------------------------------------------------

typedef __attribute__((ext_vector_type(8))) __bf16 bf16x8;
typedef __attribute__((ext_vector_type(8))) unsigned short u16x8;
typedef __attribute__((ext_vector_type(4))) float f32x4;

__device__ __forceinline__ unsigned short f2bf(float x) {
  unsigned u = __builtin_bit_cast(unsigned, x);
  u += 0x7fffu + ((u >> 16) & 1u);        // RNE
  return (unsigned short)(u >> 16);
}
__device__ __forceinline__ float bf2f(unsigned short b) {
  return __builtin_bit_cast(float, ((unsigned)b) << 16);
}

__device__ __forceinline__ void glds16(const unsigned short* g, unsigned short* l) {
  __builtin_amdgcn_global_load_lds(
      (const __attribute__((address_space(1))) void*)g,
      (__attribute__((address_space(3))) void*)l, 16, 0, 0);
}

// m204 bijective XCD chunk swizzle.
__device__ __forceinline__ int xcd_swz(int orig, int nwg) {
  int q = nwg >> 3, r = nwg & 7;
  int xcd = orig & 7, idx = orig >> 3;
  int base = (xcd < r) ? xcd * (q + 1) : r * (q + 1) + (xcd - r) * q;
  return base + idx;
}

// ---------------------------------------------------------------------------
// Weight convert+transpose: W f32 [K][N] -> WT bf16 [N][K].
// ---------------------------------------------------------------------------
__global__ __launch_bounds__(256) void convert_w(
    const float* __restrict__ W, unsigned short* __restrict__ WT,
    int K, int N)
{
  __shared__ unsigned short T[64][66];
  const float* Wz = W + (size_t)blockIdx.z * K * N;
  unsigned short* WTz = WT + (size_t)blockIdx.z * K * N;
  const int k0 = blockIdx.x * 64, n0 = blockIdx.y * 64;
  const int tid = threadIdx.x;
  #pragma unroll
  for (int i = tid; i < 64 * 16; i += 256) {
    int k = i >> 4, n4 = (i & 15) * 4;
    float4 v = *(const float4*)&Wz[(size_t)(k0 + k) * N + n0 + n4];
    T[n4 + 0][k] = f2bf(v.x);
    T[n4 + 1][k] = f2bf(v.y);
    T[n4 + 2][k] = f2bf(v.z);
    T[n4 + 3][k] = f2bf(v.w);
  }
  __syncthreads();
  #pragma unroll
  for (int i = tid; i < 64 * 8; i += 256) {
    int n = i >> 3, k8 = (i & 7) * 8;
    *(u16x8*)&WTz[(size_t)(n0 + n) * K + k0 + k8] = *(const u16x8*)&T[n][k8];
  }
}

// ---------------------------------------------------------------------------
// Dense GEMM: C[M,N] = A[M,K] @ BT[N,K]^T (+resid). bf16 in, f32 out.
// 128x128 tile, counted-vmcnt dbuf pipeline (unchanged from r8).
// ---------------------------------------------------------------------------
__global__ __launch_bounds__(256) void gemm_bb(
    const unsigned short* __restrict__ A, const unsigned short* __restrict__ BT,
    float* __restrict__ C, const float* __restrict__ resid,
    int M, int N, int K)
{
  __shared__ unsigned short As[2][128 * 64];
  __shared__ unsigned short Bs[2][128 * 64];
  const int mb = M >> 7;
  const int w = xcd_swz(blockIdx.x, gridDim.x);
  const int bm = (w % mb) * 128, bn = (w / mb) * 128;
  const int tid = threadIdx.x, lane = tid & 63, wid = tid >> 6;
  const int wm = (wid >> 1) * 64, wn = (wid & 1) * 64;
  const int l16 = lane & 15, g4 = lane >> 4;
  const int rseg = lane >> 3;
  const int csw  = ((lane & 7) ^ rseg) * 8;
  const unsigned short* aSrc[4];
  const unsigned short* bSrc[4];
  #pragma unroll
  for (int p = 0; p < 4; ++p) {
    int row = (p * 4 + wid) * 8 + rseg;
    aSrc[p] = A  + (size_t)(bm + row) * K + csw;
    bSrc[p] = BT + (size_t)(bn + row) * K + csw;
  }
  f32x4 acc[4][4] = {};
  const int NT = K >> 6;
  #pragma unroll
  for (int p = 0; p < 4; ++p) glds16(aSrc[p], &As[0][(p * 4 + wid) * 512]);
  #pragma unroll
  for (int p = 0; p < 4; ++p) glds16(bSrc[p], &Bs[0][(p * 4 + wid) * 512]);
  for (int t = 0; t < NT; ++t) {
    const int cur = t & 1;
    if (t + 1 < NT) {
      const int k0 = (t + 1) << 6;
      #pragma unroll
      for (int p = 0; p < 4; ++p) glds16(aSrc[p] + k0, &As[cur ^ 1][(p * 4 + wid) * 512]);
      #pragma unroll
      for (int p = 0; p < 4; ++p) glds16(bSrc[p] + k0, &Bs[cur ^ 1][(p * 4 + wid) * 512]);
      asm volatile("s_waitcnt vmcnt(8)" ::: "memory");
    } else {
      asm volatile("s_waitcnt vmcnt(0)" ::: "memory");
    }
    __builtin_amdgcn_s_barrier();
    __builtin_amdgcn_sched_barrier(0);
    const unsigned short* ab = &As[cur][0];
    const unsigned short* bb = &Bs[cur][0];
    #pragma unroll
    for (int ks = 0; ks < 2; ++ks) {
      bf16x8 af[4], bf[4];
      #pragma unroll
      for (int i = 0; i < 4; ++i) {
        int ra = wm + i * 16 + l16;
        int rb = wn + i * 16 + l16;
        int ch = ((ks * 4 + g4) ^ (l16 & 7)) * 8;
        af[i] = *(const bf16x8*)&ab[ra * 64 + ch];
        bf[i] = *(const bf16x8*)&bb[rb * 64 + ch];
      }
      #pragma unroll
      for (int mi = 0; mi < 4; ++mi)
        #pragma unroll
        for (int ni = 0; ni < 4; ++ni)
          acc[mi][ni] = __builtin_amdgcn_mfma_f32_16x16x32_bf16(af[mi], bf[ni], acc[mi][ni], 0, 0, 0);
    }
    __builtin_amdgcn_sched_barrier(0);
    __builtin_amdgcn_s_barrier();
  }
  const int r4 = g4 * 4;
  #pragma unroll
  for (int mi = 0; mi < 4; ++mi)
    #pragma unroll
    for (int ni = 0; ni < 4; ++ni)
      #pragma unroll
      for (int r = 0; r < 4; ++r) {
        int row = bm + wm + mi * 16 + r4 + r;
        int col = bn + wn + ni * 16 + l16;
        float v = acc[mi][ni][r];
        if (resid) v += resid[(size_t)row * N + col];
        C[(size_t)row * N + col] = v;
      }
}

// ---------------------------------------------------------------------------
// Expert-batched MoE GEMM, 256x256 tile, 512 threads (8 waves as 2x4, each
// 128x64). BK=64, single-buffer 64KB LDS, 2-barrier schedule. 1D grid
// 8bm x 8bn x 8e = 512, XCD-swizzled -> one expert per XCD.
// ---------------------------------------------------------------------------
__global__ __launch_bounds__(512, 1) void gemm_moe_256(
    const unsigned short* __restrict__ A, const unsigned short* __restrict__ BTall,
    float* __restrict__ C,
    const int* __restrict__ counts, const int* __restrict__ offsets,
    const int* __restrict__ pair_token, const unsigned short* __restrict__ zbuf,
    int gather, int K, int N)
{
  const int w = xcd_swz(blockIdx.x, gridDim.x);
  const int e = w >> 6;
  const int cnt = counts[e];
  const int bm = (w & 7) * 256;
  if (bm >= cnt) return;
  const int base = offsets[e];
  const int bn = ((w >> 3) & 7) * 256;
  __shared__ unsigned short As[256 * 64];
  __shared__ unsigned short Bs[256 * 64];
  __shared__ int rowmap[256];
  const int tid = threadIdx.x, lane = tid & 63, wid = tid >> 6;
  const int wr = wid >> 2, wc = wid & 3;          // wave tile 128x64 at (wr,wc)
  const int l16 = lane & 15, g4 = lane >> 4;
  const int rseg = lane >> 3;
  const int csw  = ((lane & 7) ^ rseg) * 8;
  if (tid < 256) {
    int lr = bm + tid;
    rowmap[tid] = (lr < cnt) ? (gather ? pair_token[base + lr] : base + lr) : -1;
  }
  __syncthreads();
  const unsigned short* BT = BTall + (size_t)e * N * K;
  const unsigned short* aSrc[4];
  const unsigned short* bSrc[4];
  #pragma unroll
  for (int p = 0; p < 4; ++p) {
    int row = (p * 8 + wid) * 8 + rseg;           // 0..255
    int tok = rowmap[row];
    aSrc[p] = (tok >= 0) ? (A + (size_t)tok * K + csw) : (zbuf + csw);
    bSrc[p] = BT + (size_t)(bn + row) * K + csw;
  }
  int aOk[4];
  #pragma unroll
  for (int p = 0; p < 4; ++p) aOk[p] = (rowmap[(p * 8 + wid) * 8 + rseg] >= 0);
  f32x4 acc[8][4] = {};
  const int NT = K >> 6;
  for (int t = 0; t < NT; ++t) {
    const int k0 = t << 6;
    #pragma unroll
    for (int p = 0; p < 4; ++p)
      glds16(aSrc[p] + (aOk[p] ? k0 : 0), &As[(p * 8 + wid) * 512]);
    #pragma unroll
    for (int p = 0; p < 4; ++p)
      glds16(bSrc[p] + k0, &Bs[(p * 8 + wid) * 512]);
    __syncthreads();
    #pragma unroll
    for (int ks = 0; ks < 2; ++ks) {
      const int ch = ((ks * 4 + g4) ^ (l16 & 7)) * 8;
      bf16x8 bf[4];
      #pragma unroll
      for (int j = 0; j < 4; ++j)
        bf[j] = *(const bf16x8*)&Bs[(wc * 64 + j * 16 + l16) * 64 + ch];
      #pragma unroll
      for (int mi = 0; mi < 8; ++mi) {
        bf16x8 af = *(const bf16x8*)&As[(wr * 128 + mi * 16 + l16) * 64 + ch];
        #pragma unroll
        for (int ni = 0; ni < 4; ++ni)
          acc[mi][ni] = __builtin_amdgcn_mfma_f32_16x16x32_bf16(af, bf[ni], acc[mi][ni], 0, 0, 0);
      }
    }
    __syncthreads();
  }
  const int r4 = g4 * 4;
  #pragma unroll
  for (int mi = 0; mi < 8; ++mi)
    #pragma unroll
    for (int ni = 0; ni < 4; ++ni)
      #pragma unroll
      for (int r = 0; r < 4; ++r) {
        int lrow = bm + wr * 128 + mi * 16 + r4 + r;
        int col  = bn + wc * 64 + ni * 16 + l16;
        if (lrow < cnt)
          C[(size_t)(base + lrow) * N + col] = acc[mi][ni][r];
      }
}

// ---------------------------------------------------------------------------
// RMSNorm over D=2048, f32 in -> bf16 out (+ optional exact f32 out).
// ---------------------------------------------------------------------------
__global__ __launch_bounds__(256) void rmsnorm_rows(
    const float* __restrict__ in, const float* __restrict__ w,
    unsigned short* __restrict__ out, float* __restrict__ out32)
{
  const int row = blockIdx.x;
  const int tid = threadIdx.x;
  const float* x = in + (size_t)row * 2048;
  float4 a = *(const float4*)&x[tid * 8];
  float4 b = *(const float4*)&x[tid * 8 + 4];
  float s = a.x*a.x + a.y*a.y + a.z*a.z + a.w*a.w
          + b.x*b.x + b.y*b.y + b.z*b.z + b.w*b.w;
  #pragma unroll
  for (int off = 1; off < 64; off <<= 1) s += __shfl_xor(s, off);
  __shared__ float red[4];
  if ((tid & 63) == 0) red[tid >> 6] = s;
  __syncthreads();
  float inv = rsqrtf((red[0] + red[1] + red[2] + red[3]) * (1.f / 2048.f) + 1e-6f);
  float4 wa = *(const float4*)&w[tid * 8];
  float4 wb = *(const float4*)&w[tid * 8 + 4];
  float y[8] = {a.x * inv * wa.x, a.y * inv * wa.y, a.z * inv * wa.z, a.w * inv * wa.w,
                b.x * inv * wb.x, b.y * inv * wb.y, b.z * inv * wb.z, b.w * inv * wb.w};
  unsigned short* o = out + (size_t)row * 2048 + tid * 8;
  #pragma unroll
  for (int j = 0; j < 8; ++j) o[j] = f2bf(y[j]);
  if (out32) {
    float* o32 = out32 + (size_t)row * 2048 + tid * 8;
    *(float4*)&o32[0] = make_float4(y[0], y[1], y[2], y[3]);
    *(float4*)&o32[4] = make_float4(y[4], y[5], y[6], y[7]);
  }
}

__global__ __launch_bounds__(256) void f32_to_bf16_k(
    const float* __restrict__ in, unsigned short* __restrict__ out, int n)
{
  int i = (blockIdx.x * 256 + threadIdx.x) * 4;
  if (i + 3 < n) {
    float4 v = *(const float4*)&in[i];
    out[i + 0] = f2bf(v.x); out[i + 1] = f2bf(v.y);
    out[i + 2] = f2bf(v.z); out[i + 3] = f2bf(v.w);
  }
}

// ---------------------------------------------------------------------------
// Per-(b,s,h) head RMSNorm + RoPE, relayout to (B, NH, seq_total, 128) bf16.
// ---------------------------------------------------------------------------
__global__ __launch_bounds__(256) void qk_norm_rope(
    const float* __restrict__ raw, int ld, const float* __restrict__ nw,
    const float* __restrict__ cosT, const float* __restrict__ sinT,
    unsigned short* __restrict__ out,
    int S, int NH, int seq_total, int s_off, float premul)
{
  int rowid = blockIdx.x * 4 + (threadIdx.x >> 6);
  int lane  = threadIdx.x & 63;
  int b = rowid / (S * NH);
  int rem = rowid % (S * NH);
  int s = rem / NH, h = rem % NH;
  const float* src = raw + (size_t)(b * S + s) * ld + h * 128;
  float2 xv = *(const float2*)&src[lane * 2];
  float ss = xv.x * xv.x + xv.y * xv.y;
  #pragma unroll
  for (int off = 1; off < 64; off <<= 1) ss += __shfl_xor(ss, off);
  float inv = rsqrtf(ss * (1.f / 128.f) + 1e-6f);
  float yr = xv.x * inv * nw[lane * 2];
  float yi = xv.y * inv * nw[lane * 2 + 1];
  float c  = cosT[s * 64 + lane], sn = sinT[s * 64 + lane];
  float orr = (yr * c - yi * sn) * premul;
  float oi  = (yr * sn + yi * c) * premul;
  unsigned short* dst = out + ((size_t)(b * NH + h) * seq_total + (s + s_off)) * 128;
  dst[lane * 2]     = f2bf(orr);
  dst[lane * 2 + 1] = f2bf(oi);
}

__global__ __launch_bounds__(256) void v_relayout(
    const float* __restrict__ raw, int ld, unsigned short* __restrict__ out,
    int S, int NH, int seq_total, int s_off)
{
  int rowid = blockIdx.x * 4 + (threadIdx.x >> 6);
  int lane  = threadIdx.x & 63;
  int b = rowid / (S * NH);
  int rem = rowid % (S * NH);
  int s = rem / NH, h = rem % NH;
  const float* src = raw + (size_t)(b * S + s) * ld + h * 128;
  float2 xv = *(const float2*)&src[lane * 2];
  unsigned short* dst = out + ((size_t)(b * NH + h) * seq_total + (s + s_off)) * 128;
  dst[lane * 2]     = f2bf(xv.x);
  dst[lane * 2 + 1] = f2bf(xv.y);
}

// ---------------------------------------------------------------------------
// Flash attention (unchanged from r8): XOR-swizzled LDS + async dbuf reg
// staging, 64 q-rows/block, Sk tiles of 64.
// ---------------------------------------------------------------------------
__global__ __launch_bounds__(256) void attn_kernel(
    const unsigned short* __restrict__ q,
    const unsigned short* __restrict__ kbuf,
    const unsigned short* __restrict__ vbuf,
    unsigned short* __restrict__ o)
{
  const int SK = 1536;
  const int w = xcd_swz(blockIdx.x, gridDim.x);
  const int bh = w >> 4;
  const int b = bh >> 4, h = bh & 15, kvh = h >> 2;
  const int q0 = (w & 15) * 64;
  const int tid = threadIdx.x, lane = tid & 63, wid = tid >> 6;
  const int l16 = lane & 15, kb = (lane >> 4) * 8, r4 = (lane >> 4) * 4;
  __shared__ unsigned short KsL[64 * 128];
  __shared__ unsigned short VTL[128 * 64];
  __shared__ unsigned short PsL[4 * 16 * 64];
  const int sr0 = tid >> 4;
  const int scc = (tid & 15) * 8;

  const unsigned short* qrow =
      q + ((size_t)(b * 16 + h) * 1024 + q0 + wid * 16 + l16) * 128;
  bf16x8 qf[4];
  #pragma unroll
  for (int ks = 0; ks < 4; ++ks) qf[ks] = *(const bf16x8*)&qrow[ks * 32 + kb];
  float mrow[4] = {-1e30f, -1e30f, -1e30f, -1e30f};
  float lrow[4] = {0.f, 0.f, 0.f, 0.f};
  f32x4 oacc[8] = {};
  const unsigned short* kb_base = kbuf + (size_t)(b * 4 + kvh) * SK * 128;
  const unsigned short* vb_base = vbuf + (size_t)(b * 4 + kvh) * SK * 128;

  u16x8 k0[4], v0[4], k1[4], v1[4];

#define ATT_LOAD(kr, vr, kt1)                                                 \
  {                                                                           \
    _Pragma("unroll")                                                         \
    for (int i = 0; i < 4; ++i) {                                             \
      kr[i] = *(const u16x8*)&kb_base[(size_t)((kt1) + sr0 + 16 * i) * 128 + scc]; \
      vr[i] = *(const u16x8*)&vb_base[(size_t)((kt1) + sr0 + 16 * i) * 128 + scc]; \
    }                                                                         \
  }

#define ATT_STAGE(kr, vr)                                                     \
  {                                                                           \
    _Pragma("unroll")                                                         \
    for (int i = 0; i < 4; ++i) {                                             \
      int rr = sr0 + 16 * i;                                                  \
      *(u16x8*)&KsL[rr * 128 + (((scc >> 3) ^ (rr & 7)) << 3)] = kr[i];       \
      _Pragma("unroll")                                                       \
      for (int j = 0; j < 8; ++j)                                             \
        VTL[(scc + j) * 64 + ((((rr >> 3) ^ ((scc + j) >> 3)) & 7) << 3) + (rr & 7)] = vr[i][j]; \
    }                                                                         \
  }

  auto compute = [&]() {
    f32x4 sacc[4] = {};
    #pragma unroll
    for (int ks = 0; ks < 4; ++ks) {
      #pragma unroll
      for (int ni = 0; ni < 4; ++ni) {
        int rr = ni * 16 + l16;
        bf16x8 kf = *(const bf16x8*)
            &KsL[rr * 128 + ((((ks * 32 + kb) >> 3) ^ (rr & 7)) << 3)];
        sacc[ni] = __builtin_amdgcn_mfma_f32_16x16x32_bf16(qf[ks], kf, sacc[ni], 0, 0, 0);
      }
    }
    float pv[4][4], alpha[4];
    #pragma unroll
    for (int r = 0; r < 4; ++r) {
      float tm = fmaxf(fmaxf(sacc[0][r], sacc[1][r]), fmaxf(sacc[2][r], sacc[3][r]));
      #pragma unroll
      for (int off = 1; off < 16; off <<= 1) tm = fmaxf(tm, __shfl_xor(tm, off));
      float mn = fmaxf(mrow[r], tm);
      alpha[r] = __expf(mrow[r] - mn);
      float s = 0.f;
      #pragma unroll
      for (int ni = 0; ni < 4; ++ni) {
        float p = __expf(sacc[ni][r] - mn);
        pv[ni][r] = p; s += p;
      }
      #pragma unroll
      for (int off = 1; off < 16; off <<= 1) s += __shfl_xor(s, off);
      lrow[r] = lrow[r] * alpha[r] + s;
      mrow[r] = mn;
    }
    #pragma unroll
    for (int ni = 0; ni < 8; ++ni)
      #pragma unroll
      for (int r = 0; r < 4; ++r) oacc[ni][r] *= alpha[r];
    #pragma unroll
    for (int ni = 0; ni < 4; ++ni)
      #pragma unroll
      for (int r = 0; r < 4; ++r) {
        int row = r4 + r, col = ni * 16 + l16;
        PsL[wid * 1024 + row * 64 + ((((col >> 3) ^ (row & 7)) & 7) << 3) + (col & 7)]
            = f2bf(pv[ni][r]);
      }
    asm volatile("s_waitcnt lgkmcnt(0)" ::: "memory");
    __builtin_amdgcn_sched_barrier(0);
    #pragma unroll
    for (int ks = 0; ks < 2; ++ks) {
      bf16x8 pf = *(const bf16x8*)
          &PsL[wid * 1024 + l16 * 64 + ((((ks * 32 + kb) >> 3) ^ (l16 & 7)) << 3)];
      #pragma unroll
      for (int ni = 0; ni < 8; ++ni) {
        int d = ni * 16 + l16;
        bf16x8 vf = *(const bf16x8*)
            &VTL[d * 64 + ((((ks * 32 + kb) >> 3) ^ ((d >> 3) & 7)) << 3)];
        oacc[ni] = __builtin_amdgcn_mfma_f32_16x16x32_bf16(pf, vf, oacc[ni], 0, 0, 0);
      }
    }
  };

  ATT_LOAD(k0, v0, 0);
  for (int t = 0; t < 24; t += 2) {
    ATT_STAGE(k0, v0);
    ATT_LOAD(k1, v1, (t + 1) * 64);
    asm volatile("s_waitcnt lgkmcnt(0)" ::: "memory");
    __builtin_amdgcn_s_barrier();
    __builtin_amdgcn_sched_barrier(0);
    compute();
    __builtin_amdgcn_sched_barrier(0);
    __builtin_amdgcn_s_barrier();
    ATT_STAGE(k1, v1);
    if (t + 2 < 24) ATT_LOAD(k0, v0, (t + 2) * 64);
    asm volatile("s_waitcnt lgkmcnt(0)" ::: "memory");
    __builtin_amdgcn_s_barrier();
    __builtin_amdgcn_sched_barrier(0);
    compute();
    __builtin_amdgcn_sched_barrier(0);
    __builtin_amdgcn_s_barrier();
  }
#undef ATT_LOAD
#undef ATT_STAGE

  #pragma unroll
  for (int ni = 0; ni < 8; ++ni)
    #pragma unroll
    for (int r = 0; r < 4; ++r) {
      float val = oacc[ni][r] / lrow[r];
      size_t row = (size_t)b * 1024 + q0 + wid * 16 + r4 + r;
      o[row * 2048 + h * 128 + ni * 16 + l16] = f2bf(val);
    }
}

// ---------------------------------------------------------------------------
// Router: one wave per token, f32 input (exact), f32 accumulate.
// ---------------------------------------------------------------------------
__global__ __launch_bounds__(64) void router_kernel(
    const float* __restrict__ xt32, const float* __restrict__ rw,
    int* __restrict__ topi, float* __restrict__ topw, int* __restrict__ counts)
{
  int t = blockIdx.x, lane = threadIdx.x;
  float acc[8] = {};
  const float* x = xt32 + (size_t)t * 2048;
  for (int d0 = lane * 4; d0 < 2048; d0 += 256) {
    float4 xv = *(const float4*)&x[d0];
    float xa[4] = {xv.x, xv.y, xv.z, xv.w};
    #pragma unroll
    for (int j = 0; j < 4; ++j) {
      const float4 r0 = *(const float4*)&rw[(d0 + j) * 8];
      const float4 r1 = *(const float4*)&rw[(d0 + j) * 8 + 4];
      acc[0] += xa[j] * r0.x; acc[1] += xa[j] * r0.y;
      acc[2] += xa[j] * r0.z; acc[3] += xa[j] * r0.w;
      acc[4] += xa[j] * r1.x; acc[5] += xa[j] * r1.y;
      acc[6] += xa[j] * r1.z; acc[7] += xa[j] * r1.w;
    }
  }
  #pragma unroll
  for (int e = 0; e < 8; ++e)
    #pragma unroll
    for (int off = 1; off < 64; off <<= 1) acc[e] += __shfl_xor(acc[e], off);
  if (lane == 0) {
    float v0 = acc[0]; int e0 = 0;
    #pragma unroll
    for (int e = 1; e < 8; ++e) if (acc[e] > v0) { v0 = acc[e]; e0 = e; }
    float v1 = -1e30f; int e1 = 0;
    #pragma unroll
    for (int e = 0; e < 8; ++e) if (e != e0 && acc[e] > v1) { v1 = acc[e]; e1 = e; }
    float x1 = expf(v1 - v0);
    float w0 = 1.f / (1.f + x1);
    float w1 = x1 / (1.f + x1);
    topi[2 * t] = e0; topi[2 * t + 1] = e1;
    topw[2 * t] = w0; topw[2 * t + 1] = w1;
    atomicAdd(&counts[e0], 1);
    atomicAdd(&counts[e1], 1);
  }
}

__global__ void scan_offsets(const int* __restrict__ counts, int* __restrict__ offsets)
{
  if (threadIdx.x == 0 && blockIdx.x == 0) {
    int a = 0;
    for (int e = 0; e < 8; ++e) { offsets[e] = a; a += counts[e]; }
    offsets[8] = a;
  }
}

__global__ __launch_bounds__(256) void scatter_pairs(
    const int* __restrict__ topi, const int* __restrict__ offsets,
    int* __restrict__ fill, int* __restrict__ pair_token, int* __restrict__ token_slot)
{
  int t = blockIdx.x * 256 + threadIdx.x;
  if (t >= 2048) return;
  #pragma unroll
  for (int k = 0; k < 2; ++k) {
    int e = topi[2 * t + k];
    int slot = offsets[e] + atomicAdd(&fill[e], 1);
    pair_token[slot] = t;
    token_slot[2 * t + k] = slot;
  }
}

__global__ __launch_bounds__(256) void act_silu(
    const float* __restrict__ gu, unsigned short* __restrict__ act)
{
  int p = blockIdx.x;
  int c = threadIdx.x * 4;
  float4 g = *(const float4*)&gu[(size_t)p * 2048 + c];
  float4 u = *(const float4*)&gu[(size_t)p * 2048 + 1024 + c];
  float gg[4] = {g.x, g.y, g.z, g.w};
  float uu[4] = {u.x, u.y, u.z, u.w};
  #pragma unroll
  for (int j = 0; j < 4; ++j) {
    float a = gg[j] / (1.f + __expf(-gg[j])) * uu[j];
    act[(size_t)p * 1024 + c + j] = f2bf(a);
  }
}

__global__ __launch_bounds__(256) void moe_combine(
    float* __restrict__ out, const float* __restrict__ eo,
    const int* __restrict__ token_slot, const float* __restrict__ topw)
{
  int t = blockIdx.x;
  int c = threadIdx.x * 8;
  int s0 = token_slot[2 * t], s1 = token_slot[2 * t + 1];
  float w0 = topw[2 * t], w1 = topw[2 * t + 1];
  #pragma unroll
  for (int j0 = 0; j0 < 8; j0 += 4) {
    float4 a = *(const float4*)&eo[(size_t)s0 * 2048 + c + j0];
    float4 b = *(const float4*)&eo[(size_t)s1 * 2048 + c + j0];
    float4 v = *(const float4*)&out[(size_t)t * 2048 + c + j0];
    v.x += w0 * a.x + w1 * b.x;
    v.y += w0 * a.y + w1 * b.y;
    v.z += w0 * a.z + w1 * b.z;
    v.w += w0 * a.w + w1 * b.w;
    *(float4*)&out[(size_t)t * 2048 + c + j0] = v;
  }
}

// ---------------------------------------------------------------------------
extern "C" void kernel_launch(void* const* d_in, const int* in_sizes, int n_in,
                              void* d_out, int out_size, void* d_ws, size_t ws_size,
                              hipStream_t stream)
{
  const float* hidden  = (const float*)d_in[0];
  const float* enc     = (const float*)d_in[1];
  const float* img_cos = (const float*)d_in[2];
  const float* img_sin = (const float*)d_in[3];
  const float* txt_cos = (const float*)d_in[4];
  const float* txt_sin = (const float*)d_in[5];
  const float* norm1_w = (const float*)d_in[6];
  const float* norm2_w = (const float*)d_in[7];
  const float* wq      = (const float*)d_in[8];
  const float* wk      = (const float*)d_in[9];
  const float* wv      = (const float*)d_in[10];
  const float* wk_txt  = (const float*)d_in[11];
  const float* wv_txt  = (const float*)d_in[12];
  const float* wo      = (const float*)d_in[13];
  const float* q_norm_w       = (const float*)d_in[14];
  const float* k_norm_w       = (const float*)d_in[15];
  const float* added_k_norm_w = (const float*)d_in[16];
  const float* router_w       = (const float*)d_in[17];
  const float* gate_up_proj   = (const float*)d_in[18];
  const float* down_proj      = (const float*)d_in[19];
  float* out = (float*)d_out;

  char* ws = (char*)d_ws;
  size_t off = 0;
  auto alloc = [&](size_t bytes) {
    void* p = ws + off;
    off += (bytes + 255) & ~(size_t)255;
    return p;
  };
  // --- bf16 transposed weights ---
  unsigned short* wqkvT  = (unsigned short*)alloc(3072ULL * 2048 * 2); // q|k|v rows
  unsigned short* wkvtT  = (unsigned short*)alloc(1024ULL * 2048 * 2); // k_txt|v_txt
  unsigned short* woT    = (unsigned short*)alloc(2048ULL * 2048 * 2);
  unsigned short* gupT   = (unsigned short*)alloc(8ULL * 2048 * 2048 * 2);
  unsigned short* dnT    = (unsigned short*)alloc(8ULL * 2048 * 1024 * 2);
  // --- activations ---
  unsigned short* x_bf   = (unsigned short*)alloc(2048ULL * 2048 * 2);
  unsigned short* enc_bf = (unsigned short*)alloc(1024ULL * 2048 * 2);
  float* qkvC = (float*)alloc(4096ULL * 2048 * 4); // [2048][3072] early; gu [4096][2048] late
  float* gu   = qkvC;                              // alias (disjoint lifetimes)
  float* kvtC = (float*)alloc(1024ULL * 1024 * 4); // [1024][1024] k_txt|v_txt
  unsigned short* qb   = (unsigned short*)alloc(2048ULL * 2048 * 2);
  unsigned short* kbuf = (unsigned short*)alloc(2ULL * 4 * 1536 * 128 * 2);
  unsigned short* vbuf = (unsigned short*)alloc(2ULL * 4 * 1536 * 128 * 2);
  unsigned short* obuf = (unsigned short*)alloc(2048ULL * 2048 * 2);
  unsigned short* act  = obuf;                     // alias (obuf dead after wo GEMM)
  unsigned short* xt   = (unsigned short*)alloc(2048ULL * 2048 * 2);
  float* xt32 = (float*)alloc(2048ULL * 2048 * 4);
  int*   ctrl  = (int*)alloc(64 * sizeof(int));    // counts[8] fill[8] offsets[9]
  int*   topi  = (int*)alloc(4096 * 4);
  float* topw  = (float*)alloc(4096 * 4);
  int*   tslot = (int*)alloc(4096 * 4);
  int*   ptok  = (int*)alloc(4096 * 4);
  unsigned short* zbuf = (unsigned short*)alloc(256);
  int* counts = ctrl, * fill = ctrl + 8, * offsets = ctrl + 16;

  hipMemsetAsync(ctrl, 0, 64, stream);
  hipMemsetAsync(zbuf, 0, 256, stream);

  const float scale = 0.08838834764831845f;  // 1/sqrt(128)

  // --- weight preprocessing: f32 [K][N] -> bf16 [N][K] ---
  convert_w<<<dim3(32, 32, 1), 256, 0, stream>>>(wq,     wqkvT,                    2048, 2048);
  convert_w<<<dim3(32,  8, 1), 256, 0, stream>>>(wk,     wqkvT + 2048ULL * 2048,   2048, 512);
  convert_w<<<dim3(32,  8, 1), 256, 0, stream>>>(wv,     wqkvT + 2560ULL * 2048,   2048, 512);
  convert_w<<<dim3(32,  8, 1), 256, 0, stream>>>(wk_txt, wkvtT,                    2048, 512);
  convert_w<<<dim3(32,  8, 1), 256, 0, stream>>>(wv_txt, wkvtT + 512ULL * 2048,    2048, 512);
  convert_w<<<dim3(32, 32, 1), 256, 0, stream>>>(wo,     woT,                      2048, 2048);
  convert_w<<<dim3(32, 32, 8), 256, 0, stream>>>(gate_up_proj, gupT,               2048, 2048);
  convert_w<<<dim3(16, 32, 8), 256, 0, stream>>>(down_proj,    dnT,                1024, 2048);

  rmsnorm_rows<<<2048, 256, 0, stream>>>(hidden, norm1_w, x_bf, nullptr);
  f32_to_bf16_k<<<2048, 256, 0, stream>>>(enc, enc_bf, 1024 * 2048);

  // fused qkv projection: [2048][2048] @ [3072][2048]^T -> [2048][3072]
  gemm_bb<<<384, 256, 0, stream>>>(x_bf, wqkvT, qkvC, nullptr, 2048, 3072, 2048);
  // fused k/v txt projection: [1024][2048] @ [1024][2048]^T -> [1024][1024]
  gemm_bb<<<64, 256, 0, stream>>>(enc_bf, wkvtT, kvtC, nullptr, 1024, 1024, 2048);

  qk_norm_rope<<<8192, 256, 0, stream>>>(qkvC, 3072, q_norm_w, img_cos, img_sin, qb,
                                         1024, 16, 1024, 0, scale);
  qk_norm_rope<<<2048, 256, 0, stream>>>(qkvC + 2048, 3072, k_norm_w, img_cos, img_sin, kbuf,
                                         1024, 4, 1536, 0, 1.0f);
  qk_norm_rope<<<1024, 256, 0, stream>>>(kvtC, 1024, added_k_norm_w, txt_cos, txt_sin, kbuf,
                                         512, 4, 1536, 1024, 1.0f);
  v_relayout<<<2048, 256, 0, stream>>>(qkvC + 2560, 3072, vbuf, 1024, 4, 1536, 0);
  v_relayout<<<1024, 256, 0, stream>>>(kvtC + 512, 1024, vbuf, 512, 4, 1536, 1024);

  attn_kernel<<<512, 256, 0, stream>>>(qb, kbuf, vbuf, obuf);

  gemm_bb<<<256, 256, 0, stream>>>(obuf, woT, out, hidden, 2048, 2048, 2048);

  rmsnorm_rows<<<2048, 256, 0, stream>>>(out, norm2_w, xt, xt32);
  router_kernel<<<2048, 64, 0, stream>>>(xt32, router_w, topi, topw, counts);
  scan_offsets<<<1, 64, 0, stream>>>(counts, offsets);
  scatter_pairs<<<8, 256, 0, stream>>>(topi, offsets, fill, ptok, tslot);

  gemm_moe_256<<<512, 512, 0, stream>>>(xt, gupT, gu,
                                        counts, offsets, ptok, zbuf, 1, 2048, 2048);
  act_silu<<<4096, 256, 0, stream>>>(gu, act);
  gemm_moe_256<<<512, 512, 0, stream>>>(act, dnT, gu,
                                        counts, offsets, ptok, zbuf, 0, 1024, 2048);
  moe_combine<<<2048, 256, 0, stream>>>(out, gu, tslot, topw);
}